// Round 5
// baseline (14105.624 us; speedup 1.0000x reference)
//
#include <hip/hip_runtime.h>
#include <cstdint>
#include <cmath>

// ---------------- problem constants ----------------
#define DD      768
#define FFD     3072
#define NH      12
#define HDIM    64
#define LAYERS  3
#define CSZ     512
#define NB      256
#define NC      32
#define NSEQ    (NB * NC * 2)   // 16384 sequences
#define NTOK    (NSEQ * 2)      // 32768 token rows

typedef unsigned short ushort_t;
using short8 = __attribute__((ext_vector_type(8))) short;
using f32x4  = __attribute__((ext_vector_type(4))) float;

static __device__ __forceinline__ float b2f(ushort_t u) {
    union { float f; uint32_t i; } x; x.i = ((uint32_t)u) << 16; return x.f;
}
static __device__ __forceinline__ ushort_t f2b(float f) {
    uint32_t i = __float_as_uint(f);
    uint32_t r = (i + 0x7fffu + ((i >> 16) & 1u)) >> 16;   // RNE
    return (ushort_t)r;
}
static __device__ __forceinline__ float gelu_f(float x) {
    return 0.5f * x * (1.0f + erff(x * 0.70710678118654752f));
}
static __device__ __forceinline__ float wave_sum64(float v) {
#pragma unroll
    for (int off = 32; off > 0; off >>= 1) v += __shfl_xor(v, off, 64);
    return v;
}
static __device__ __forceinline__ void async_cp16(const void* g, void* l) {
    __builtin_amdgcn_global_load_lds((const __attribute__((address_space(1))) void*)g,
                                     (__attribute__((address_space(3))) void*)l, 16, 0, 0);
}
// raw workgroup barrier (does NOT drain vmcnt)
static __device__ __forceinline__ void wg_barrier() {
    asm volatile("" ::: "memory");
    __builtin_amdgcn_s_barrier();
    asm volatile("" ::: "memory");
}
#define WAITVM(N) asm volatile("s_waitcnt vmcnt(" #N ")" ::: "memory")
#define LDSFENCE() asm volatile("s_waitcnt lgkmcnt(0)" ::: "memory")

// ---------------- fp32 -> bf16 convert (n % 4 == 0) ----------------
__global__ __launch_bounds__(256) void cvt_bf16(const float* __restrict__ s,
                                                ushort_t* __restrict__ d, int n) {
    const int i = (blockIdx.x * 256 + threadIdx.x) * 4;
    if (i < n) {
        const float4 v = *(const float4*)(s + i);
        ushort4 o;
        o.x = f2b(v.x); o.y = f2b(v.y); o.z = f2b(v.z); o.w = f2b(v.w);
        *(ushort4*)(d + i) = o;
    }
}

// ---------------- build x0 (bf16): [32768][768] ----------------
__global__ __launch_bounds__(192) void build_x(const float* __restrict__ parent,
                                               const float* __restrict__ child,
                                               ushort_t* __restrict__ X) {
    const int r = blockIdx.x;
    const int t = threadIdx.x;        // 192 threads * 4 = 768
    const int n = r >> 1, q = r & 1;
    const int i = n >> 6;
    const int k = (n >> 1) & 31;
    const int j = n & 1;
    const float* src = (q == 0) ? (parent + (size_t)i * DD)
                                : (child + ((size_t)((i * 32 + k) * 2 + (1 - j))) * DD);
    const float4 v = ((const float4*)src)[t];
    ushort4 o;
    o.x = f2b(v.x); o.y = f2b(v.y); o.z = f2b(v.z); o.w = f2b(v.w);
    ((ushort4*)(X + (size_t)r * DD))[t] = o;
}

// ---------------- bf16 MFMA NT GEMM (legacy 128x128, used for small shapes) ----------------
__global__ __launch_bounds__(256) void gemm_bf16(const ushort_t* __restrict__ A, int lda,
                                                 const ushort_t* __restrict__ W,
                                                 const float* __restrict__ bias,
                                                 ushort_t* __restrict__ C, int ldc,
                                                 int K, int NT, int GM, int GN,
                                                 int dogelu) {
    __shared__ __align__(16) short smem[16384];   // 32 KB
    short* As = smem;
    short* Bs = smem + 8192;

    const int st = blockIdx.x / (GM * GN);
    const int stn = NT / GN;
    const int srow = st / stn, scol = st - srow * stn;
    const int r = blockIdx.x - st * (GM * GN);
    const int mt = srow * GM + r / GN;
    const int nt = scol * GN + (r - (r / GN) * GN);
    const int m0 = mt * 128;
    const int n0 = nt * 128;

    const int tid = threadIdx.x;
    const int r0s = tid >> 2, c0s = (tid & 3) * 8;
    const ushort_t* Ag0 = A + (size_t)(m0 + r0s) * lda + c0s;
    const ushort_t* Ag1 = A + (size_t)(m0 + 64 + r0s) * lda + c0s;
    const ushort_t* Wg0 = W + (size_t)(n0 + r0s) * K + c0s;
    const ushort_t* Wg1 = W + (size_t)(n0 + 64 + r0s) * K + c0s;

    const int wid = tid >> 6, lane = tid & 63;
    const int wm = (wid >> 1) * 64, wn = (wid & 1) * 64;
    const int lm = lane & 15;
    const int ko = (lane >> 4) * 8;

    f32x4 acc[4][4];
#pragma unroll
    for (int i = 0; i < 4; ++i)
#pragma unroll
        for (int j = 0; j < 4; ++j) acc[i][j] = {0.f, 0.f, 0.f, 0.f};

    {
        async_cp16(Ag0, As + tid * 8);
        async_cp16(Ag1, As + 2048 + tid * 8);
        async_cp16(Wg0, Bs + tid * 8);
        async_cp16(Wg1, Bs + 2048 + tid * 8);
    }

    for (int k0 = 0; k0 < K; k0 += 32) {
        const int b = (k0 >> 5) & 1;
        const int boff = b * 4096;
        __syncthreads();
        if (k0 + 32 < K) {
            const int o = (boff ^ 4096);
            const int k = k0 + 32;
            async_cp16(Ag0 + k, As + o + tid * 8);
            async_cp16(Ag1 + k, As + o + 2048 + tid * 8);
            async_cp16(Wg0 + k, Bs + o + tid * 8);
            async_cp16(Wg1 + k, Bs + o + 2048 + tid * 8);
        }
        short8 af[4], bfr[4];
#pragma unroll
        for (int i = 0; i < 4; ++i)
            af[i] = *(const short8*)(As + boff + (wm + i * 16 + lm) * 32 + ko);
#pragma unroll
        for (int j = 0; j < 4; ++j)
            bfr[j] = *(const short8*)(Bs + boff + (wn + j * 16 + lm) * 32 + ko);
#pragma unroll
        for (int i = 0; i < 4; ++i)
#pragma unroll
            for (int j = 0; j < 4; ++j)
                acc[i][j] = __builtin_amdgcn_mfma_f32_16x16x32_bf16(af[i], bfr[j], acc[i][j], 0, 0, 0);
    }

    float* T = (float*)smem;
    float* Tw = T + wid * 1088;
    const int r4 = lane >> 4;
    const int rrow = lane >> 2;
    const int rc0 = (lane & 3) * 16;
    const int gcolb = n0 + wn;

    float4 bb[4];
    if (bias) {
#pragma unroll
        for (int t = 0; t < 4; ++t) bb[t] = *(const float4*)(bias + gcolb + rc0 + t * 4);
    } else {
#pragma unroll
        for (int t = 0; t < 4; ++t) bb[t] = make_float4(0.f, 0.f, 0.f, 0.f);
    }

#pragma unroll
    for (int i = 0; i < 4; ++i) {
        __syncthreads();
#pragma unroll
        for (int j = 0; j < 4; ++j)
#pragma unroll
            for (int rr = 0; rr < 4; ++rr)
                Tw[(r4 * 4 + rr) * 68 + j * 16 + lm] = acc[i][j][rr];
        __syncthreads();
        float o[16];
#pragma unroll
        for (int t = 0; t < 4; ++t)
            *(f32x4*)&o[t * 4] = *(const f32x4*)(Tw + rrow * 68 + rc0 + t * 4);
#pragma unroll
        for (int t = 0; t < 4; ++t) {
            o[t * 4 + 0] += ((const float*)&bb[t])[0];
            o[t * 4 + 1] += ((const float*)&bb[t])[1];
            o[t * 4 + 2] += ((const float*)&bb[t])[2];
            o[t * 4 + 3] += ((const float*)&bb[t])[3];
        }
        if (dogelu) {
#pragma unroll
            for (int t = 0; t < 16; ++t) o[t] = gelu_f(o[t]);
        }
        uint32_t pk[8];
#pragma unroll
        for (int t = 0; t < 8; ++t)
            pk[t] = (uint32_t)f2b(o[2 * t]) | ((uint32_t)f2b(o[2 * t + 1]) << 16);
        ushort_t* dst = C + (size_t)(m0 + wm + i * 16 + rrow) * ldc + gcolb + rc0;
        *(uint4*)dst = make_uint4(pk[0], pk[1], pk[2], pk[3]);
        *(uint4*)(dst + 8) = make_uint4(pk[4], pk[5], pk[6], pk[7]);
    }
}

// ---------------- 128x256 8-wave GEMM, 48KB LDS -> 3 blocks/CU (inter-block TLP) ----------------
// C[M x N](bf16) = act( A[M x K](bf16, lda) @ W[N x K]^T + bias(f32) )
// Requirements: M%128==0, N%256==0, K%32==0. Grid=(M/128)*(N/256), 512 thr.
// Per-wave 64x64 output (acc = 64 f32 regs, VGPR=64 measured). __launch_bounds__(512,6)
// => 6 waves/SIMD = THREE co-resident blocks per CU (LDS 3x48=144KB <= 160KB).
// Latency/barrier stalls of one block are filled by the other blocks' waves (m114
// mechanism; r4 A/B: 1->2 blocks was +18% on this exact kernel). One barrier per
// K-step; stage-after-barrier is WAR-safe; vmcnt(0) drain covered by co-resident blocks.
__global__ __launch_bounds__(512, 6) void gemm_mid(const ushort_t* __restrict__ A, int lda,
                                                   const ushort_t* __restrict__ W,
                                                   const float* __restrict__ bias,
                                                   ushort_t* __restrict__ C, int ldc,
                                                   int K, int NT, int GM, int GN,
                                                   int dogelu) {
    __shared__ __align__(16) short smem[24576];   // 48 KB: 2 x (A 8KB + B 16KB)
    const int tid = threadIdx.x;

    // ---- bijective XCD remap (m204), then supertile decode ----
    const int nwg = gridDim.x;
    const int bid = blockIdx.x;
    const int qx = nwg >> 3, rx = nwg & 7;
    const int xcd = bid & 7, pos = bid >> 3;
    const int wgid = (xcd < rx ? xcd * (qx + 1) : rx * (qx + 1) + (xcd - rx) * qx) + pos;
    const int stb = GM * GN;
    const int st = wgid / stb;
    const int stn = NT / GN;
    const int srow = st / stn, scol = st - srow * stn;
    const int r = wgid - st * stb;
    const int mt = srow * GM + r / GN;
    const int nt = scol * GN + (r - (r / GN) * GN);
    const int m0 = mt * 128, n0 = nt * 256;

    // ---- staging (pre-swizzled global source, linear LDS dest) ----
    const int srow_t = tid >> 2;                                  // 0..127
    const int scol_t = ((tid & 3) ^ ((tid >> 3) & 3)) << 3;       // swizzled col (elems)
    const ushort_t* Ag = A + (size_t)(m0 + srow_t) * lda + scol_t;
    const ushort_t* Bg = W + (size_t)(n0 + srow_t) * K + scol_t;
    const size_t ldbH = (size_t)128 * K;
    short* ldsA = smem + tid * 8;                 // A region: [0,4096) shorts per buf
    short* ldsB = smem + 4096 + tid * 8;          // B region: [4096,12288) per buf

    auto stage = [&](int s_) {                    // stage K-step s_ into buf s_&1 (3 issues)
        const int b_ = (s_ & 1) * 12288;
        const int k_ = s_ * 32;
        async_cp16(Ag + k_,        ldsA + b_);
        async_cp16(Bg + k_,        ldsB + b_);
        async_cp16(Bg + ldbH + k_, ldsB + b_ + 4096);
    };

    // ---- fragment read addresses (swizzled; same involution as staging) ----
    const int wid = tid >> 6, lane = tid & 63;
    const int wr = wid >> 2, wc = wid & 3;        // 2 x 4 wave grid; wave tile 64x64
    const int lm = lane & 15;
    const int swz = (((lane >> 4) ^ ((lane >> 1) & 3)) << 3);
    const short* rdA0 = smem + (wr * 64 + lm) * 32 + swz;
    const short* rdB0 = smem + 4096 + (wc * 64 + lm) * 32 + swz;

    f32x4 acc[4][4];
#pragma unroll
    for (int i = 0; i < 4; ++i)
#pragma unroll
        for (int j = 0; j < 4; ++j) acc[i][j] = {0.f, 0.f, 0.f, 0.f};

    const int NS = K >> 5;
    stage(0);
    for (int s = 0; s < NS; ++s) {
        const int boff = (s & 1) * 12288;
        WAITVM(0);                 // this wave's stage(s) retired (<=3 loads outstanding)
        wg_barrier();              // all waves: step s visible; reads of buf s^1 retired
        if (s + 1 < NS) stage(s + 1);
        short8 af[4], bf[4];
#pragma unroll
        for (int i = 0; i < 4; ++i) af[i] = *(const short8*)(rdA0 + boff + i * 512);
#pragma unroll
        for (int j = 0; j < 4; ++j) bf[j] = *(const short8*)(rdB0 + boff + j * 512);
#pragma unroll
        for (int i = 0; i < 4; ++i)
#pragma unroll
            for (int j = 0; j < 4; ++j)
                acc[i][j] = __builtin_amdgcn_mfma_f32_16x16x32_bf16(af[i], bf[j], acc[i][j], 0, 0, 0);
    }
    wg_barrier();                  // epilogue Tw region overlaps staging buffers

    // ---- epilogue: per-wave-private LDS transpose -> uint4 bf16 stores ----
    float* Tw = (float*)smem + wid * 1088;        // 16*68 floats per wave (34.8 KB total)
    const int r4 = lane >> 4;
    const int rrow = lane >> 2;
    const int rc0 = (lane & 3) * 16;
    const int gcolb = n0 + wc * 64;

    float4 bb[4];
#pragma unroll
    for (int t = 0; t < 4; ++t) bb[t] = *(const float4*)(bias + gcolb + rc0 + t * 4);

#pragma unroll
    for (int mi = 0; mi < 4; ++mi) {
#pragma unroll
        for (int j = 0; j < 4; ++j)
#pragma unroll
            for (int rr = 0; rr < 4; ++rr)
                Tw[(r4 * 4 + rr) * 68 + j * 16 + lm] = acc[mi][j][rr];
        LDSFENCE();
        float o[16];
#pragma unroll
        for (int t = 0; t < 4; ++t)
            *(f32x4*)&o[t * 4] = *(const f32x4*)(Tw + rrow * 68 + rc0 + t * 4);
#pragma unroll
        for (int t = 0; t < 4; ++t) {
            o[t * 4 + 0] += ((const float*)&bb[t])[0];
            o[t * 4 + 1] += ((const float*)&bb[t])[1];
            o[t * 4 + 2] += ((const float*)&bb[t])[2];
            o[t * 4 + 3] += ((const float*)&bb[t])[3];
        }
        if (dogelu) {
#pragma unroll
            for (int t = 0; t < 16; ++t) o[t] = gelu_f(o[t]);
        }
        uint32_t pk[8];
#pragma unroll
        for (int t = 0; t < 8; ++t)
            pk[t] = (uint32_t)f2b(o[2 * t]) | ((uint32_t)f2b(o[2 * t + 1]) << 16);
        ushort_t* dst = C + (size_t)(m0 + wr * 64 + mi * 16 + rrow) * ldc + gcolb + rc0;
        *(uint4*)dst = make_uint4(pk[0], pk[1], pk[2], pk[3]);
        *(uint4*)(dst + 8) = make_uint4(pk[4], pk[5], pk[6], pk[7]);
        LDSFENCE();
    }
}

// ---------------- pe projections ----------------
__global__ __launch_bounds__(256) void pe_proj(const float* __restrict__ pel,
                                               const float* __restrict__ aiwl,
                                               float* __restrict__ PEQ,
                                               float* __restrict__ PEK) {
    const int wid = threadIdx.x >> 6, lane = threadIdx.x & 63;
    const int task = blockIdx.x * 4 + wid;
    const int which = task >= 3 * DD;
    const int idx = task - which * 3 * DD;
    const int r = idx / DD, o = idx - r * DD;
    const float* pe = pel + (size_t)r * DD;
    const float* w = aiwl + (size_t)(which ? DD + o : o) * DD;
    float s = 0.f;
#pragma unroll
    for (int e = 0; e < 12; ++e) s += pe[e * 64 + lane] * w[e * 64 + lane];
    s = wave_sum64(s);
    if (lane == 0) (which ? PEK : PEQ)[r * DD + o] = s;
}

// ---------------- attention (seq len 2), one wave per (sequence, head) ----------------
__global__ __launch_bounds__(256) void attn_kernel(const ushort_t* __restrict__ QKV,
                                                   const float* __restrict__ peq,
                                                   const float* __restrict__ pek,
                                                   ushort_t* __restrict__ O,
                                                   int seq0) {
    const int wid = threadIdx.x >> 6;
    const int lane = threadIdx.x & 63;
    const int task = blockIdx.x * 4 + wid;
    const int ns = task / NH;
    const int h = task - ns * NH;
    const int j = (seq0 + ns) & 1;
    const ushort_t* base = QKV + (size_t)(2 * ns) * (3 * DD);
    const int c = h * HDIM + lane;
    const int role1 = (1 + j) * DD;

    const float q0 = b2f(base[c]) + peq[c];
    const float k0 = b2f(base[DD + c]) + pek[c];
    const float v0 = b2f(base[2 * DD + c]);
    const ushort_t* base1 = base + 3 * DD;
    const float q1 = b2f(base1[c]) + peq[role1 + c];
    const float k1 = b2f(base1[DD + c]) + pek[role1 + c];
    const float v1 = b2f(base1[2 * DD + c]);

    float p00 = q0 * k0, p01 = q0 * k1, p10 = q1 * k0, p11 = q1 * k1;
#pragma unroll
    for (int off = 32; off > 0; off >>= 1) {
        p00 += __shfl_xor(p00, off, 64);
        p01 += __shfl_xor(p01, off, 64);
        p10 += __shfl_xor(p10, off, 64);
        p11 += __shfl_xor(p11, off, 64);
    }
    const float sc = 0.125f;
    const float s00 = p00 * sc, s01 = p01 * sc, s10 = p10 * sc, s11 = p11 * sc;

    const float m0 = fmaxf(s00, s01);
    const float e00 = __expf(s00 - m0), e01 = __expf(s01 - m0);
    const float a00 = e00 / (e00 + e01);
    const float o0 = a00 * v0 + (1.0f - a00) * v1;

    const float m1 = fmaxf(s10, s11);
    const float e10 = __expf(s10 - m1), e11 = __expf(s11 - m1);
    const float a10 = e10 / (e10 + e11);
    const float o1 = a10 * v0 + (1.0f - a10) * v1;

    O[(size_t)(2 * ns) * DD + c] = f2b(o0);
    O[(size_t)(2 * ns + 1) * DD + c] = f2b(o1);
}

// ---------------- x = inorm(x + d), bf16 in/out, one wave per row ----------------
__global__ __launch_bounds__(256) void add_inorm(ushort_t* __restrict__ x,
                                                 const ushort_t* __restrict__ d) {
    const int wid = threadIdx.x >> 6, lane = threadIdx.x & 63;
    const int r = blockIdx.x * 4 + wid;
    ushort_t* xr = x + (size_t)r * DD;
    const ushort_t* dr = d + (size_t)r * DD;
    float v[12];
    float s = 0.f, ss = 0.f;
#pragma unroll
    for (int e = 0; e < 3; ++e) {
        const ushort4 xa = ((const ushort4*)xr)[e * 64 + lane];
        const ushort4 da = ((const ushort4*)dr)[e * 64 + lane];
        const float a0 = b2f(xa.x) + b2f(da.x);
        const float a1 = b2f(xa.y) + b2f(da.y);
        const float a2 = b2f(xa.z) + b2f(da.z);
        const float a3 = b2f(xa.w) + b2f(da.w);
        v[e * 4 + 0] = a0; v[e * 4 + 1] = a1; v[e * 4 + 2] = a2; v[e * 4 + 3] = a3;
        s += a0 + a1 + a2 + a3;
        ss += a0 * a0 + a1 * a1 + a2 * a2 + a3 * a3;
    }
    s = wave_sum64(s); ss = wave_sum64(ss);
    const float mean = s * (1.0f / DD);
    const float var = ss * (1.0f / DD) - mean * mean;
    const float rs = rsqrtf(var + 1e-5f);
#pragma unroll
    for (int e = 0; e < 3; ++e) {
        ushort4 o;
        o.x = f2b((v[e * 4 + 0] - mean) * rs);
        o.y = f2b((v[e * 4 + 1] - mean) * rs);
        o.z = f2b((v[e * 4 + 2] - mean) * rs);
        o.w = f2b((v[e * 4 + 3] - mean) * rs);
        ((ushort4*)xr)[e * 64 + lane] = o;
    }
}

// ---------------- final: out[n] = inorm(x[2n] + x[2n+1]) fp32 out ----------------
__global__ __launch_bounds__(256) void final_inorm(const ushort_t* __restrict__ x,
                                                   float* __restrict__ out) {
    const int wid = threadIdx.x >> 6, lane = threadIdx.x & 63;
    const int n = blockIdx.x * 4 + wid;
    const ushort_t* r0 = x + (size_t)(2 * n) * DD;
    const ushort_t* r1 = r0 + DD;
    float v[12];
    float s = 0.f, ss = 0.f;
#pragma unroll
    for (int e = 0; e < 3; ++e) {
        const ushort4 xa = ((const ushort4*)r0)[e * 64 + lane];
        const ushort4 xb = ((const ushort4*)r1)[e * 64 + lane];
        const float a0 = b2f(xa.x) + b2f(xb.x);
        const float a1 = b2f(xa.y) + b2f(xb.y);
        const float a2 = b2f(xa.z) + b2f(xb.z);
        const float a3 = b2f(xa.w) + b2f(xb.w);
        v[e * 4 + 0] = a0; v[e * 4 + 1] = a1; v[e * 4 + 2] = a2; v[e * 4 + 3] = a3;
        s += a0 + a1 + a2 + a3;
        ss += a0 * a0 + a1 * a1 + a2 * a2 + a3 * a3;
    }
    s = wave_sum64(s); ss = wave_sum64(ss);
    const float mean = s * (1.0f / DD);
    const float var = ss * (1.0f / DD) - mean * mean;
    const float rs = rsqrtf(var + 1e-5f);
    float* orow = out + (size_t)n * DD;
#pragma unroll
    for (int e = 0; e < 3; ++e) {
        float4 o;
        o.x = (v[e * 4 + 0] - mean) * rs;
        o.y = (v[e * 4 + 1] - mean) * rs;
        o.z = (v[e * 4 + 2] - mean) * rs;
        o.w = (v[e * 4 + 3] - mean) * rs;
        ((float4*)orow)[e * 64 + lane] = o;
    }
}

// ---------------- scores ----------------
__global__ __launch_bounds__(256) void score_dot(const ushort_t* __restrict__ pc,
                                                 const ushort_t* __restrict__ cc,
                                                 float* __restrict__ out, int which) {
    const int wid = threadIdx.x >> 6;
    const int lane = threadIdx.x & 63;
    const int row = blockIdx.x * 4 + wid;
    const int b = row >> 5;
    const ushort_t* p = pc + (size_t)b * CSZ;
    const ushort_t* c = cc + (size_t)row * CSZ;
    float s = 0.f;
#pragma unroll
    for (int e = 0; e < 8; ++e) s += b2f(p[e * 64 + lane]) * b2f(c[e * 64 + lane]);
    s = wave_sum64(s);
    if (lane == 0) out[row * 2 + which] = s * 0.04419417382415922f; // 1/sqrt(512)
}

// ---------------- host launch ----------------
extern "C" void kernel_launch(void* const* d_in, const int* in_sizes, int n_in,
                              void* d_out, int out_size, void* d_ws, size_t ws_size,
                              hipStream_t stream) {
    const float* parent = (const float*)d_in[0];
    const float* child  = (const float*)d_in[1];
    const float* aiw = (const float*)d_in[4];
    const float* aib = (const float*)d_in[5];
    const float* aow = (const float*)d_in[6];
    const float* aob = (const float*)d_in[7];
    const float* l1w = (const float*)d_in[8];
    const float* l1b = (const float*)d_in[9];
    const float* l2w = (const float*)d_in[10];
    const float* l2b = (const float*)d_in[11];
    const float* pemb = (const float*)d_in[12];
    const float* pw1 = (const float*)d_in[13];
    const float* pb1 = (const float*)d_in[14];
    const float* pw2 = (const float*)d_in[15];
    const float* pb2 = (const float*)d_in[16];
    const float* lw1 = (const float*)d_in[17];
    const float* lb1 = (const float*)d_in[18];
    const float* lw2 = (const float*)d_in[19];
    const float* lb2 = (const float*)d_in[20];
    const float* rw1 = (const float*)d_in[21];
    const float* rb1 = (const float*)d_in[22];
    const float* rw2 = (const float*)d_in[23];
    const float* rb2 = (const float*)d_in[24];
    float* out = (float*)d_out;
    (void)in_sizes; (void)n_in; (void)out_size;

    // ---- pick chunk rows from workspace ----
    int CH = 8192;
    {
        const size_t fixedB = 100ull * 1024 * 1024;
        if (ws_size >= fixedB + (size_t)32768 * 4608 * 2) CH = 32768;
        else if (ws_size >= fixedB + (size_t)16384 * 4608 * 2) CH = 16384;
    }
    const int NCH = NTOK / CH;

    ushort_t* W0 = (ushort_t*)d_ws;
    size_t off = 0;
    auto take = [&](size_t elems) { ushort_t* p = W0 + off; off += (elems + 127) & ~(size_t)127; return p; };
    ushort_t* aiw_b = take((size_t)LAYERS * 3 * DD * DD);
    ushort_t* aow_b = take((size_t)LAYERS * DD * DD);
    ushort_t* l1w_b = take((size_t)LAYERS * FFD * DD);
    ushort_t* l2w_b = take((size_t)LAYERS * DD * FFD);
    ushort_t* pw1_b = take((size_t)DD * DD);
    ushort_t* pw2_b = take((size_t)CSZ * DD);
    ushort_t* lw1_b = take((size_t)DD * DD);
    ushort_t* lw2_b = take((size_t)CSZ * DD);
    ushort_t* rw1_b = take((size_t)DD * DD);
    ushort_t* rw2_b = take((size_t)CSZ * DD);
    ushort_t* Pb    = take((size_t)NB * DD);
    ushort_t* Xb    = take((size_t)NTOK * DD);
    ushort_t* S1b   = take((size_t)CH * FFD);
    ushort_t* S2b   = take((size_t)CH * DD);
    ushort_t* S3b   = take((size_t)CH * DD);
    ushort_t* P1b   = take((size_t)NB * DD);
    ushort_t* P2b   = take((size_t)NB * CSZ);
    float* PEQ = (float*)(W0 + off); off += 2 * 3 * DD;
    float* PEK = PEQ + 3 * DD;

    auto cvt = [&](const float* s, ushort_t* d, size_t n) {
        cvt_bf16<<<(int)((n + 1023) / 1024), 256, 0, stream>>>(s, d, (int)n);
    };
    auto gemm = [&](const ushort_t* A, int lda, const ushort_t* Wt, const float* bias,
                    ushort_t* C, int ldc, int M, int N, int K, int dg) {
        if (M % 128 == 0 && N % 256 == 0 && M >= 8192 && N >= 768 && K % 32 == 0) {
            const int MT = M / 128, NT = N / 256;
            const int GM = (MT % 8 == 0) ? 8 : ((MT % 4 == 0) ? 4 : MT);
            int GN = 8;
            while (NT % GN) --GN;
            gemm_mid<<<MT * NT, 512, 0, stream>>>(A, lda, Wt, bias, C, ldc, K, NT, GM, GN, dg);
        } else {
            const int MT = M / 128, NT = N / 128;
            const int GM = (MT % 8 == 0) ? 8 : MT;
            int GN = 8;
            while (NT % GN) --GN;
            gemm_bf16<<<MT * NT, 256, 0, stream>>>(A, lda, Wt, bias, C, ldc, K, NT, GM, GN, dg);
        }
    };

    // ---- weight / input conversions ----
    cvt(aiw, aiw_b, (size_t)LAYERS * 3 * DD * DD);
    cvt(aow, aow_b, (size_t)LAYERS * DD * DD);
    cvt(l1w, l1w_b, (size_t)LAYERS * FFD * DD);
    cvt(l2w, l2w_b, (size_t)LAYERS * DD * FFD);
    cvt(pw1, pw1_b, (size_t)DD * DD);
    cvt(pw2, pw2_b, (size_t)CSZ * DD);
    cvt(lw1, lw1_b, (size_t)DD * DD);
    cvt(lw2, lw2_b, (size_t)CSZ * DD);
    cvt(rw1, rw1_b, (size_t)DD * DD);
    cvt(rw2, rw2_b, (size_t)CSZ * DD);
    cvt(parent, Pb, (size_t)NB * DD);
    cvt(child, S1b, (size_t)NB * NC * 2 * DD);   // child bf16 into S1b [16384][768]

    // ---- build x0 ----
    build_x<<<NTOK, 192, 0, stream>>>(parent, child, Xb);

    // ---- outside scores ----
    gemm(Pb, DD, pw1_b, pb1, P1b, DD, NB, DD, DD, 1);
    gemm(P1b, DD, pw2_b, pb2, P2b, CSZ, NB, CSZ, DD, 0);
    gemm(S1b, 2 * DD, lw1_b, lb1, S2b, DD, NB * NC, DD, DD, 1);
    gemm(S2b, DD, lw2_b, lb2, S3b, CSZ, NB * NC, CSZ, DD, 0);
    score_dot<<<NB * NC / 4, 256, 0, stream>>>(P2b, S3b, out, 1);
    gemm(S1b + DD, 2 * DD, rw1_b, rb1, S2b, DD, NB * NC, DD, DD, 1);
    gemm(S2b, DD, rw2_b, rb2, S3b, CSZ, NB * NC, CSZ, DD, 0);
    score_dot<<<NB * NC / 4, 256, 0, stream>>>(P2b, S3b, out, 0);

    // ---- transformer layers ----
    for (int l = 0; l < LAYERS; ++l) {
        const ushort_t* Wl  = aiw_b + (size_t)l * 3 * DD * DD;
        const float* bl  = aib + (size_t)l * 3 * DD;
        const ushort_t* owl = aow_b + (size_t)l * DD * DD;
        const float* obl = aob + (size_t)l * DD;
        const ushort_t* w1l = l1w_b + (size_t)l * FFD * DD;
        const float* b1l = l1b + (size_t)l * FFD;
        const ushort_t* w2l = l2w_b + (size_t)l * DD * FFD;
        const float* b2l = l2b + (size_t)l * DD;

        pe_proj<<<2 * 3 * DD / 4, 256, 0, stream>>>(pemb + (size_t)l * 4 * DD,
                                                    aiw + (size_t)l * 3 * DD * DD, PEQ, PEK);

        for (int c = 0; c < NCH; ++c) {
            ushort_t* Xc = Xb + (size_t)c * CH * DD;
            gemm(Xc, DD, Wl, bl, S1b, 3 * DD, CH, 3 * DD, DD, 0);
            attn_kernel<<<(CH / 2) * NH / 4, 256, 0, stream>>>(S1b, PEQ, PEK, S2b, c * (CH / 2));
            gemm(S2b, DD, owl, obl, S3b, DD, CH, DD, DD, 0);
            add_inorm<<<CH / 4, 256, 0, stream>>>(Xc, S3b);
            gemm(Xc, DD, w1l, b1l, S1b, FFD, CH, FFD, DD, 1);
            gemm(S1b, FFD, w2l, b2l, S3b, DD, CH, DD, FFD, 0);
            add_inorm<<<CH / 4, 256, 0, stream>>>(Xc, S3b);
        }
    }

    // ---- final: inorm over token-sum ----
    final_inorm<<<NSEQ / 4, 256, 0, stream>>>(Xb, out + NSEQ);
}

// Round 6
// 2476.031 us; speedup vs baseline: 5.6969x; 5.6969x over previous
//
#include <hip/hip_runtime.h>
#include <cstdint>
#include <cmath>

// ---------------- problem constants ----------------
#define DD      768
#define FFD     3072
#define NH      12
#define HDIM    64
#define LAYERS  3
#define CSZ     512
#define NB      256
#define NC      32
#define NSEQ    (NB * NC * 2)   // 16384 sequences
#define NTOK    (NSEQ * 2)      // 32768 token rows

typedef unsigned short ushort_t;
using short8 = __attribute__((ext_vector_type(8))) short;
using f32x4  = __attribute__((ext_vector_type(4))) float;

static __device__ __forceinline__ float b2f(ushort_t u) {
    union { float f; uint32_t i; } x; x.i = ((uint32_t)u) << 16; return x.f;
}
static __device__ __forceinline__ ushort_t f2b(float f) {
    uint32_t i = __float_as_uint(f);
    uint32_t r = (i + 0x7fffu + ((i >> 16) & 1u)) >> 16;   // RNE
    return (ushort_t)r;
}
static __device__ __forceinline__ float gelu_f(float x) {
    return 0.5f * x * (1.0f + erff(x * 0.70710678118654752f));
}
static __device__ __forceinline__ float wave_sum64(float v) {
#pragma unroll
    for (int off = 32; off > 0; off >>= 1) v += __shfl_xor(v, off, 64);
    return v;
}
static __device__ __forceinline__ void async_cp16(const void* g, void* l) {
    __builtin_amdgcn_global_load_lds((const __attribute__((address_space(1))) void*)g,
                                     (__attribute__((address_space(3))) void*)l, 16, 0, 0);
}
// raw workgroup barrier (does NOT drain vmcnt)
static __device__ __forceinline__ void wg_barrier() {
    asm volatile("" ::: "memory");
    __builtin_amdgcn_s_barrier();
    asm volatile("" ::: "memory");
}
#define WAITVM(N) asm volatile("s_waitcnt vmcnt(" #N ")" ::: "memory")
#define LDSFENCE() asm volatile("s_waitcnt lgkmcnt(0)" ::: "memory")

// ---------------- fp32 -> bf16 convert (n % 4 == 0) ----------------
__global__ __launch_bounds__(256) void cvt_bf16(const float* __restrict__ s,
                                                ushort_t* __restrict__ d, int n) {
    const int i = (blockIdx.x * 256 + threadIdx.x) * 4;
    if (i < n) {
        const float4 v = *(const float4*)(s + i);
        ushort4 o;
        o.x = f2b(v.x); o.y = f2b(v.y); o.z = f2b(v.z); o.w = f2b(v.w);
        *(ushort4*)(d + i) = o;
    }
}

// ---------------- build x0 (bf16): [32768][768] ----------------
__global__ __launch_bounds__(192) void build_x(const float* __restrict__ parent,
                                               const float* __restrict__ child,
                                               ushort_t* __restrict__ X) {
    const int r = blockIdx.x;
    const int t = threadIdx.x;        // 192 threads * 4 = 768
    const int n = r >> 1, q = r & 1;
    const int i = n >> 6;
    const int k = (n >> 1) & 31;
    const int j = n & 1;
    const float* src = (q == 0) ? (parent + (size_t)i * DD)
                                : (child + ((size_t)((i * 32 + k) * 2 + (1 - j))) * DD);
    const float4 v = ((const float4*)src)[t];
    ushort4 o;
    o.x = f2b(v.x); o.y = f2b(v.y); o.z = f2b(v.z); o.w = f2b(v.w);
    ((ushort4*)(X + (size_t)r * DD))[t] = o;
}

// ---------------- bf16 MFMA NT GEMM (legacy 128x128, used for small shapes) ----------------
__global__ __launch_bounds__(256) void gemm_bf16(const ushort_t* __restrict__ A, int lda,
                                                 const ushort_t* __restrict__ W,
                                                 const float* __restrict__ bias,
                                                 ushort_t* __restrict__ C, int ldc,
                                                 int K, int NT, int GM, int GN,
                                                 int dogelu) {
    __shared__ __align__(16) short smem[16384];   // 32 KB
    short* As = smem;
    short* Bs = smem + 8192;

    const int st = blockIdx.x / (GM * GN);
    const int stn = NT / GN;
    const int srow = st / stn, scol = st - srow * stn;
    const int r = blockIdx.x - st * (GM * GN);
    const int mt = srow * GM + r / GN;
    const int nt = scol * GN + (r - (r / GN) * GN);
    const int m0 = mt * 128;
    const int n0 = nt * 128;

    const int tid = threadIdx.x;
    const int r0s = tid >> 2, c0s = (tid & 3) * 8;
    const ushort_t* Ag0 = A + (size_t)(m0 + r0s) * lda + c0s;
    const ushort_t* Ag1 = A + (size_t)(m0 + 64 + r0s) * lda + c0s;
    const ushort_t* Wg0 = W + (size_t)(n0 + r0s) * K + c0s;
    const ushort_t* Wg1 = W + (size_t)(n0 + 64 + r0s) * K + c0s;

    const int wid = tid >> 6, lane = tid & 63;
    const int wm = (wid >> 1) * 64, wn = (wid & 1) * 64;
    const int lm = lane & 15;
    const int ko = (lane >> 4) * 8;

    f32x4 acc[4][4];
#pragma unroll
    for (int i = 0; i < 4; ++i)
#pragma unroll
        for (int j = 0; j < 4; ++j) acc[i][j] = {0.f, 0.f, 0.f, 0.f};

    {
        async_cp16(Ag0, As + tid * 8);
        async_cp16(Ag1, As + 2048 + tid * 8);
        async_cp16(Wg0, Bs + tid * 8);
        async_cp16(Wg1, Bs + 2048 + tid * 8);
    }

    for (int k0 = 0; k0 < K; k0 += 32) {
        const int b = (k0 >> 5) & 1;
        const int boff = b * 4096;
        __syncthreads();
        if (k0 + 32 < K) {
            const int o = (boff ^ 4096);
            const int k = k0 + 32;
            async_cp16(Ag0 + k, As + o + tid * 8);
            async_cp16(Ag1 + k, As + o + 2048 + tid * 8);
            async_cp16(Wg0 + k, Bs + o + tid * 8);
            async_cp16(Wg1 + k, Bs + o + 2048 + tid * 8);
        }
        short8 af[4], bfr[4];
#pragma unroll
        for (int i = 0; i < 4; ++i)
            af[i] = *(const short8*)(As + boff + (wm + i * 16 + lm) * 32 + ko);
#pragma unroll
        for (int j = 0; j < 4; ++j)
            bfr[j] = *(const short8*)(Bs + boff + (wn + j * 16 + lm) * 32 + ko);
#pragma unroll
        for (int i = 0; i < 4; ++i)
#pragma unroll
            for (int j = 0; j < 4; ++j)
                acc[i][j] = __builtin_amdgcn_mfma_f32_16x16x32_bf16(af[i], bfr[j], acc[i][j], 0, 0, 0);
    }

    float* T = (float*)smem;
    float* Tw = T + wid * 1088;
    const int r4 = lane >> 4;
    const int rrow = lane >> 2;
    const int rc0 = (lane & 3) * 16;
    const int gcolb = n0 + wn;

    float4 bb[4];
    if (bias) {
#pragma unroll
        for (int t = 0; t < 4; ++t) bb[t] = *(const float4*)(bias + gcolb + rc0 + t * 4);
    } else {
#pragma unroll
        for (int t = 0; t < 4; ++t) bb[t] = make_float4(0.f, 0.f, 0.f, 0.f);
    }

#pragma unroll
    for (int i = 0; i < 4; ++i) {
        __syncthreads();
#pragma unroll
        for (int j = 0; j < 4; ++j)
#pragma unroll
            for (int rr = 0; rr < 4; ++rr)
                Tw[(r4 * 4 + rr) * 68 + j * 16 + lm] = acc[i][j][rr];
        __syncthreads();
        float o[16];
#pragma unroll
        for (int t = 0; t < 4; ++t)
            *(f32x4*)&o[t * 4] = *(const f32x4*)(Tw + rrow * 68 + rc0 + t * 4);
#pragma unroll
        for (int t = 0; t < 4; ++t) {
            o[t * 4 + 0] += ((const float*)&bb[t])[0];
            o[t * 4 + 1] += ((const float*)&bb[t])[1];
            o[t * 4 + 2] += ((const float*)&bb[t])[2];
            o[t * 4 + 3] += ((const float*)&bb[t])[3];
        }
        if (dogelu) {
#pragma unroll
            for (int t = 0; t < 16; ++t) o[t] = gelu_f(o[t]);
        }
        uint32_t pk[8];
#pragma unroll
        for (int t = 0; t < 8; ++t)
            pk[t] = (uint32_t)f2b(o[2 * t]) | ((uint32_t)f2b(o[2 * t + 1]) << 16);
        ushort_t* dst = C + (size_t)(m0 + wm + i * 16 + rrow) * ldc + gcolb + rc0;
        *(uint4*)dst = make_uint4(pk[0], pk[1], pk[2], pk[3]);
        *(uint4*)(dst + 8) = make_uint4(pk[4], pk[5], pk[6], pk[7]);
    }
}

// ---------------- 128x128 4-wave GEMM, 32KB LDS -> 4 blocks/CU (inter-block TLP) ----------------
// C[M x N](bf16) = act( A[M x K](bf16, lda) @ W[N x K]^T + bias(f32) )
// Requirements: M%128==0, N%128==0, K%32==0. Grid=(M/128)*(N/128), 256 thr (4 waves).
// Per-wave 64x64 output (acc = 64 regs; unified VGPR+acc = 128 -> 4 waves/SIMD ceiling,
// measured r4; r5 ERRATA: forcing 6 waves/EU spills acc to scratch, WRITE_SIZE x15).
// __launch_bounds__(256,4): 4 waves/EU = FOUR independent 4-wave blocks per CU
// (LDS 4x32=128KB <= 160KB). Same wave count as the r4 2x8-wave config but twice the
// independent barrier groups -- each group's WAITVM(0)+barrier drain is covered by 3
// other groups at random phases (m114 mechanism; 1->2 groups was +18% on r4's A/B).
// Stage-after-barrier WAR-safe; swizzle involution proven conflict-free (r1..r4).
__global__ __launch_bounds__(256, 4) void gemm_mid(const ushort_t* __restrict__ A, int lda,
                                                   const ushort_t* __restrict__ W,
                                                   const float* __restrict__ bias,
                                                   ushort_t* __restrict__ C, int ldc,
                                                   int K, int NT, int GM, int GN,
                                                   int dogelu) {
    __shared__ __align__(16) short smem[16384];   // 32 KB: 2 x (A 8KB + B 8KB)
    const int tid = threadIdx.x;

    // ---- bijective XCD remap (m204), then supertile decode ----
    const int nwg = gridDim.x;
    const int bid = blockIdx.x;
    const int qx = nwg >> 3, rx = nwg & 7;
    const int xcd = bid & 7, pos = bid >> 3;
    const int wgid = (xcd < rx ? xcd * (qx + 1) : rx * (qx + 1) + (xcd - rx) * qx) + pos;
    const int stb = GM * GN;
    const int st = wgid / stb;
    const int stn = NT / GN;
    const int srow = st / stn, scol = st - srow * stn;
    const int r = wgid - st * stb;
    const int mt = srow * GM + r / GN;
    const int nt = scol * GN + (r - (r / GN) * GN);
    const int m0 = mt * 128, n0 = nt * 128;

    // ---- staging (pre-swizzled global source, linear LDS dest) ----
    // row = tid>>2 in [0,64); slot = tid&3; swizzled slot = slot ^ ((row>>1)&3).
    // Second half-rows (r+64) use the same swizzle since (r+64)>>1 == r>>1 (mod 4).
    const int srow_t = tid >> 2;                                  // 0..63
    const int scol_t = ((tid & 3) ^ ((tid >> 3) & 3)) << 3;       // swizzled col (elems)
    const ushort_t* Ag = A + (size_t)(m0 + srow_t) * lda + scol_t;
    const ushort_t* Bg = W + (size_t)(n0 + srow_t) * K + scol_t;
    const size_t ldaH = (size_t)64 * lda;
    const size_t ldbH = (size_t)64 * K;
    short* ldsA = smem + tid * 8;                 // A region: [0,4096) shorts per buf
    short* ldsB = smem + 4096 + tid * 8;          // B region: [4096,8192) per buf

    auto stage = [&](int s_) {                    // stage K-step s_ into buf s_&1 (4 issues)
        const int b_ = (s_ & 1) * 8192;
        const int k_ = s_ * 32;
        async_cp16(Ag + k_,        ldsA + b_);
        async_cp16(Ag + ldaH + k_, ldsA + b_ + 2048);
        async_cp16(Bg + k_,        ldsB + b_);
        async_cp16(Bg + ldbH + k_, ldsB + b_ + 2048);
    };

    // ---- fragment read addresses (swizzled; same involution as staging) ----
    const int wid = tid >> 6, lane = tid & 63;
    const int wr = wid >> 1, wc = wid & 1;        // 2 x 2 wave grid; wave tile 64x64
    const int lm = lane & 15;
    const int swz = (((lane >> 4) ^ ((lane >> 1) & 3)) << 3);
    const short* rdA0 = smem + (wr * 64 + lm) * 32 + swz;
    const short* rdB0 = smem + 4096 + (wc * 64 + lm) * 32 + swz;

    f32x4 acc[4][4];
#pragma unroll
    for (int i = 0; i < 4; ++i)
#pragma unroll
        for (int j = 0; j < 4; ++j) acc[i][j] = {0.f, 0.f, 0.f, 0.f};

    const int NS = K >> 5;
    stage(0);
    for (int s = 0; s < NS; ++s) {
        const int boff = (s & 1) * 8192;
        WAITVM(0);                 // this wave's stage(s) retired (<=4 loads outstanding)
        wg_barrier();              // all waves: step s visible; reads of buf s^1 retired
        if (s + 1 < NS) stage(s + 1);
        short8 af[4], bf[4];
#pragma unroll
        for (int i = 0; i < 4; ++i) af[i] = *(const short8*)(rdA0 + boff + i * 512);
#pragma unroll
        for (int j = 0; j < 4; ++j) bf[j] = *(const short8*)(rdB0 + boff + j * 512);
#pragma unroll
        for (int i = 0; i < 4; ++i)
#pragma unroll
            for (int j = 0; j < 4; ++j)
                acc[i][j] = __builtin_amdgcn_mfma_f32_16x16x32_bf16(af[i], bf[j], acc[i][j], 0, 0, 0);
    }
    wg_barrier();                  // epilogue Tw region overlaps staging buffers

    // ---- epilogue: per-wave-private LDS transpose -> uint4 bf16 stores ----
    float* Tw = (float*)smem + wid * 1088;        // 16*68 floats per wave (17.4 KB total)
    const int r4 = lane >> 4;
    const int rrow = lane >> 2;
    const int rc0 = (lane & 3) * 16;
    const int gcolb = n0 + wc * 64;

    float4 bb[4];
#pragma unroll
    for (int t = 0; t < 4; ++t) bb[t] = *(const float4*)(bias + gcolb + rc0 + t * 4);

#pragma unroll
    for (int mi = 0; mi < 4; ++mi) {
#pragma unroll
        for (int j = 0; j < 4; ++j)
#pragma unroll
            for (int rr = 0; rr < 4; ++rr)
                Tw[(r4 * 4 + rr) * 68 + j * 16 + lm] = acc[mi][j][rr];
        LDSFENCE();
        float o[16];
#pragma unroll
        for (int t = 0; t < 4; ++t)
            *(f32x4*)&o[t * 4] = *(const f32x4*)(Tw + rrow * 68 + rc0 + t * 4);
#pragma unroll
        for (int t = 0; t < 4; ++t) {
            o[t * 4 + 0] += ((const float*)&bb[t])[0];
            o[t * 4 + 1] += ((const float*)&bb[t])[1];
            o[t * 4 + 2] += ((const float*)&bb[t])[2];
            o[t * 4 + 3] += ((const float*)&bb[t])[3];
        }
        if (dogelu) {
#pragma unroll
            for (int t = 0; t < 16; ++t) o[t] = gelu_f(o[t]);
        }
        uint32_t pk[8];
#pragma unroll
        for (int t = 0; t < 8; ++t)
            pk[t] = (uint32_t)f2b(o[2 * t]) | ((uint32_t)f2b(o[2 * t + 1]) << 16);
        ushort_t* dst = C + (size_t)(m0 + wr * 64 + mi * 16 + rrow) * ldc + gcolb + rc0;
        *(uint4*)dst = make_uint4(pk[0], pk[1], pk[2], pk[3]);
        *(uint4*)(dst + 8) = make_uint4(pk[4], pk[5], pk[6], pk[7]);
        LDSFENCE();
    }
}

// ---------------- pe projections ----------------
__global__ __launch_bounds__(256) void pe_proj(const float* __restrict__ pel,
                                               const float* __restrict__ aiwl,
                                               float* __restrict__ PEQ,
                                               float* __restrict__ PEK) {
    const int wid = threadIdx.x >> 6, lane = threadIdx.x & 63;
    const int task = blockIdx.x * 4 + wid;
    const int which = task >= 3 * DD;
    const int idx = task - which * 3 * DD;
    const int r = idx / DD, o = idx - r * DD;
    const float* pe = pel + (size_t)r * DD;
    const float* w = aiwl + (size_t)(which ? DD + o : o) * DD;
    float s = 0.f;
#pragma unroll
    for (int e = 0; e < 12; ++e) s += pe[e * 64 + lane] * w[e * 64 + lane];
    s = wave_sum64(s);
    if (lane == 0) (which ? PEK : PEQ)[r * DD + o] = s;
}

// ---------------- attention (seq len 2), one wave per (sequence, head) ----------------
__global__ __launch_bounds__(256) void attn_kernel(const ushort_t* __restrict__ QKV,
                                                   const float* __restrict__ peq,
                                                   const float* __restrict__ pek,
                                                   ushort_t* __restrict__ O,
                                                   int seq0) {
    const int wid = threadIdx.x >> 6;
    const int lane = threadIdx.x & 63;
    const int task = blockIdx.x * 4 + wid;
    const int ns = task / NH;
    const int h = task - ns * NH;
    const int j = (seq0 + ns) & 1;
    const ushort_t* base = QKV + (size_t)(2 * ns) * (3 * DD);
    const int c = h * HDIM + lane;
    const int role1 = (1 + j) * DD;

    const float q0 = b2f(base[c]) + peq[c];
    const float k0 = b2f(base[DD + c]) + pek[c];
    const float v0 = b2f(base[2 * DD + c]);
    const ushort_t* base1 = base + 3 * DD;
    const float q1 = b2f(base1[c]) + peq[role1 + c];
    const float k1 = b2f(base1[DD + c]) + pek[role1 + c];
    const float v1 = b2f(base1[2 * DD + c]);

    float p00 = q0 * k0, p01 = q0 * k1, p10 = q1 * k0, p11 = q1 * k1;
#pragma unroll
    for (int off = 32; off > 0; off >>= 1) {
        p00 += __shfl_xor(p00, off, 64);
        p01 += __shfl_xor(p01, off, 64);
        p10 += __shfl_xor(p10, off, 64);
        p11 += __shfl_xor(p11, off, 64);
    }
    const float sc = 0.125f;
    const float s00 = p00 * sc, s01 = p01 * sc, s10 = p10 * sc, s11 = p11 * sc;

    const float m0 = fmaxf(s00, s01);
    const float e00 = __expf(s00 - m0), e01 = __expf(s01 - m0);
    const float a00 = e00 / (e00 + e01);
    const float o0 = a00 * v0 + (1.0f - a00) * v1;

    const float m1 = fmaxf(s10, s11);
    const float e10 = __expf(s10 - m1), e11 = __expf(s11 - m1);
    const float a10 = e10 / (e10 + e11);
    const float o1 = a10 * v0 + (1.0f - a10) * v1;

    O[(size_t)(2 * ns) * DD + c] = f2b(o0);
    O[(size_t)(2 * ns + 1) * DD + c] = f2b(o1);
}

// ---------------- x = inorm(x + d), bf16 in/out, one wave per row ----------------
__global__ __launch_bounds__(256) void add_inorm(ushort_t* __restrict__ x,
                                                 const ushort_t* __restrict__ d) {
    const int wid = threadIdx.x >> 6, lane = threadIdx.x & 63;
    const int r = blockIdx.x * 4 + wid;
    ushort_t* xr = x + (size_t)r * DD;
    const ushort_t* dr = d + (size_t)r * DD;
    float v[12];
    float s = 0.f, ss = 0.f;
#pragma unroll
    for (int e = 0; e < 3; ++e) {
        const ushort4 xa = ((const ushort4*)xr)[e * 64 + lane];
        const ushort4 da = ((const ushort4*)dr)[e * 64 + lane];
        const float a0 = b2f(xa.x) + b2f(da.x);
        const float a1 = b2f(xa.y) + b2f(da.y);
        const float a2 = b2f(xa.z) + b2f(da.z);
        const float a3 = b2f(xa.w) + b2f(da.w);
        v[e * 4 + 0] = a0; v[e * 4 + 1] = a1; v[e * 4 + 2] = a2; v[e * 4 + 3] = a3;
        s += a0 + a1 + a2 + a3;
        ss += a0 * a0 + a1 * a1 + a2 * a2 + a3 * a3;
    }
    s = wave_sum64(s); ss = wave_sum64(ss);
    const float mean = s * (1.0f / DD);
    const float var = ss * (1.0f / DD) - mean * mean;
    const float rs = rsqrtf(var + 1e-5f);
#pragma unroll
    for (int e = 0; e < 3; ++e) {
        ushort4 o;
        o.x = f2b((v[e * 4 + 0] - mean) * rs);
        o.y = f2b((v[e * 4 + 1] - mean) * rs);
        o.z = f2b((v[e * 4 + 2] - mean) * rs);
        o.w = f2b((v[e * 4 + 3] - mean) * rs);
        ((ushort4*)xr)[e * 64 + lane] = o;
    }
}

// ---------------- final: out[n] = inorm(x[2n] + x[2n+1]) fp32 out ----------------
__global__ __launch_bounds__(256) void final_inorm(const ushort_t* __restrict__ x,
                                                   float* __restrict__ out) {
    const int wid = threadIdx.x >> 6, lane = threadIdx.x & 63;
    const int n = blockIdx.x * 4 + wid;
    const ushort_t* r0 = x + (size_t)(2 * n) * DD;
    const ushort_t* r1 = r0 + DD;
    float v[12];
    float s = 0.f, ss = 0.f;
#pragma unroll
    for (int e = 0; e < 3; ++e) {
        const ushort4 xa = ((const ushort4*)r0)[e * 64 + lane];
        const ushort4 xb = ((const ushort4*)r1)[e * 64 + lane];
        const float a0 = b2f(xa.x) + b2f(xb.x);
        const float a1 = b2f(xa.y) + b2f(xb.y);
        const float a2 = b2f(xa.z) + b2f(xb.z);
        const float a3 = b2f(xa.w) + b2f(xb.w);
        v[e * 4 + 0] = a0; v[e * 4 + 1] = a1; v[e * 4 + 2] = a2; v[e * 4 + 3] = a3;
        s += a0 + a1 + a2 + a3;
        ss += a0 * a0 + a1 * a1 + a2 * a2 + a3 * a3;
    }
    s = wave_sum64(s); ss = wave_sum64(ss);
    const float mean = s * (1.0f / DD);
    const float var = ss * (1.0f / DD) - mean * mean;
    const float rs = rsqrtf(var + 1e-5f);
    float* orow = out + (size_t)n * DD;
#pragma unroll
    for (int e = 0; e < 3; ++e) {
        float4 o;
        o.x = (v[e * 4 + 0] - mean) * rs;
        o.y = (v[e * 4 + 1] - mean) * rs;
        o.z = (v[e * 4 + 2] - mean) * rs;
        o.w = (v[e * 4 + 3] - mean) * rs;
        ((float4*)orow)[e * 64 + lane] = o;
    }
}

// ---------------- scores ----------------
__global__ __launch_bounds__(256) void score_dot(const ushort_t* __restrict__ pc,
                                                 const ushort_t* __restrict__ cc,
                                                 float* __restrict__ out, int which) {
    const int wid = threadIdx.x >> 6;
    const int lane = threadIdx.x & 63;
    const int row = blockIdx.x * 4 + wid;
    const int b = row >> 5;
    const ushort_t* p = pc + (size_t)b * CSZ;
    const ushort_t* c = cc + (size_t)row * CSZ;
    float s = 0.f;
#pragma unroll
    for (int e = 0; e < 8; ++e) s += b2f(p[e * 64 + lane]) * b2f(c[e * 64 + lane]);
    s = wave_sum64(s);
    if (lane == 0) out[row * 2 + which] = s * 0.04419417382415922f; // 1/sqrt(512)
}

// ---------------- host launch ----------------
extern "C" void kernel_launch(void* const* d_in, const int* in_sizes, int n_in,
                              void* d_out, int out_size, void* d_ws, size_t ws_size,
                              hipStream_t stream) {
    const float* parent = (const float*)d_in[0];
    const float* child  = (const float*)d_in[1];
    const float* aiw = (const float*)d_in[4];
    const float* aib = (const float*)d_in[5];
    const float* aow = (const float*)d_in[6];
    const float* aob = (const float*)d_in[7];
    const float* l1w = (const float*)d_in[8];
    const float* l1b = (const float*)d_in[9];
    const float* l2w = (const float*)d_in[10];
    const float* l2b = (const float*)d_in[11];
    const float* pemb = (const float*)d_in[12];
    const float* pw1 = (const float*)d_in[13];
    const float* pb1 = (const float*)d_in[14];
    const float* pw2 = (const float*)d_in[15];
    const float* pb2 = (const float*)d_in[16];
    const float* lw1 = (const float*)d_in[17];
    const float* lb1 = (const float*)d_in[18];
    const float* lw2 = (const float*)d_in[19];
    const float* lb2 = (const float*)d_in[20];
    const float* rw1 = (const float*)d_in[21];
    const float* rb1 = (const float*)d_in[22];
    const float* rw2 = (const float*)d_in[23];
    const float* rb2 = (const float*)d_in[24];
    float* out = (float*)d_out;
    (void)in_sizes; (void)n_in; (void)out_size;

    // ---- pick chunk rows from workspace ----
    int CH = 8192;
    {
        const size_t fixedB = 100ull * 1024 * 1024;
        if (ws_size >= fixedB + (size_t)32768 * 4608 * 2) CH = 32768;
        else if (ws_size >= fixedB + (size_t)16384 * 4608 * 2) CH = 16384;
    }
    const int NCH = NTOK / CH;

    ushort_t* W0 = (ushort_t*)d_ws;
    size_t off = 0;
    auto take = [&](size_t elems) { ushort_t* p = W0 + off; off += (elems + 127) & ~(size_t)127; return p; };
    ushort_t* aiw_b = take((size_t)LAYERS * 3 * DD * DD);
    ushort_t* aow_b = take((size_t)LAYERS * DD * DD);
    ushort_t* l1w_b = take((size_t)LAYERS * FFD * DD);
    ushort_t* l2w_b = take((size_t)LAYERS * DD * FFD);
    ushort_t* pw1_b = take((size_t)DD * DD);
    ushort_t* pw2_b = take((size_t)CSZ * DD);
    ushort_t* lw1_b = take((size_t)DD * DD);
    ushort_t* lw2_b = take((size_t)CSZ * DD);
    ushort_t* rw1_b = take((size_t)DD * DD);
    ushort_t* rw2_b = take((size_t)CSZ * DD);
    ushort_t* Pb    = take((size_t)NB * DD);
    ushort_t* Xb    = take((size_t)NTOK * DD);
    ushort_t* S1b   = take((size_t)CH * FFD);
    ushort_t* S2b   = take((size_t)CH * DD);
    ushort_t* S3b   = take((size_t)CH * DD);
    ushort_t* P1b   = take((size_t)NB * DD);
    ushort_t* P2b   = take((size_t)NB * CSZ);
    float* PEQ = (float*)(W0 + off); off += 2 * 3 * DD;
    float* PEK = PEQ + 3 * DD;

    auto cvt = [&](const float* s, ushort_t* d, size_t n) {
        cvt_bf16<<<(int)((n + 1023) / 1024), 256, 0, stream>>>(s, d, (int)n);
    };
    auto gemm = [&](const ushort_t* A, int lda, const ushort_t* Wt, const float* bias,
                    ushort_t* C, int ldc, int M, int N, int K, int dg) {
        if (M % 128 == 0 && N % 128 == 0 && M >= 8192 && K % 32 == 0) {
            const int MT = M / 128, NT = N / 128;
            const int GM = (MT % 8 == 0) ? 8 : ((MT % 4 == 0) ? 4 : MT);
            int GN = 8;
            while (NT % GN) --GN;
            gemm_mid<<<MT * NT, 256, 0, stream>>>(A, lda, Wt, bias, C, ldc, K, NT, GM, GN, dg);
        } else {
            const int MT = M / 128, NT = N / 128;
            const int GM = (MT % 8 == 0) ? 8 : MT;
            int GN = 8;
            while (NT % GN) --GN;
            gemm_bf16<<<MT * NT, 256, 0, stream>>>(A, lda, Wt, bias, C, ldc, K, NT, GM, GN, dg);
        }
    };

    // ---- weight / input conversions ----
    cvt(aiw, aiw_b, (size_t)LAYERS * 3 * DD * DD);
    cvt(aow, aow_b, (size_t)LAYERS * DD * DD);
    cvt(l1w, l1w_b, (size_t)LAYERS * FFD * DD);
    cvt(l2w, l2w_b, (size_t)LAYERS * DD * FFD);
    cvt(pw1, pw1_b, (size_t)DD * DD);
    cvt(pw2, pw2_b, (size_t)CSZ * DD);
    cvt(lw1, lw1_b, (size_t)DD * DD);
    cvt(lw2, lw2_b, (size_t)CSZ * DD);
    cvt(rw1, rw1_b, (size_t)DD * DD);
    cvt(rw2, rw2_b, (size_t)CSZ * DD);
    cvt(parent, Pb, (size_t)NB * DD);
    cvt(child, S1b, (size_t)NB * NC * 2 * DD);   // child bf16 into S1b [16384][768]

    // ---- build x0 ----
    build_x<<<NTOK, 192, 0, stream>>>(parent, child, Xb);

    // ---- outside scores ----
    gemm(Pb, DD, pw1_b, pb1, P1b, DD, NB, DD, DD, 1);
    gemm(P1b, DD, pw2_b, pb2, P2b, CSZ, NB, CSZ, DD, 0);
    gemm(S1b, 2 * DD, lw1_b, lb1, S2b, DD, NB * NC, DD, DD, 1);
    gemm(S2b, DD, lw2_b, lb2, S3b, CSZ, NB * NC, CSZ, DD, 0);
    score_dot<<<NB * NC / 4, 256, 0, stream>>>(P2b, S3b, out, 1);
    gemm(S1b + DD, 2 * DD, rw1_b, rb1, S2b, DD, NB * NC, DD, DD, 1);
    gemm(S2b, DD, rw2_b, rb2, S3b, CSZ, NB * NC, CSZ, DD, 0);
    score_dot<<<NB * NC / 4, 256, 0, stream>>>(P2b, S3b, out, 0);

    // ---- transformer layers ----
    for (int l = 0; l < LAYERS; ++l) {
        const ushort_t* Wl  = aiw_b + (size_t)l * 3 * DD * DD;
        const float* bl  = aib + (size_t)l * 3 * DD;
        const ushort_t* owl = aow_b + (size_t)l * DD * DD;
        const float* obl = aob + (size_t)l * DD;
        const ushort_t* w1l = l1w_b + (size_t)l * FFD * DD;
        const float* b1l = l1b + (size_t)l * FFD;
        const ushort_t* w2l = l2w_b + (size_t)l * DD * FFD;
        const float* b2l = l2b + (size_t)l * DD;

        pe_proj<<<2 * 3 * DD / 4, 256, 0, stream>>>(pemb + (size_t)l * 4 * DD,
                                                    aiw + (size_t)l * 3 * DD * DD, PEQ, PEK);

        for (int c = 0; c < NCH; ++c) {
            ushort_t* Xc = Xb + (size_t)c * CH * DD;
            gemm(Xc, DD, Wl, bl, S1b, 3 * DD, CH, 3 * DD, DD, 0);
            attn_kernel<<<(CH / 2) * NH / 4, 256, 0, stream>>>(S1b, PEQ, PEK, S2b, c * (CH / 2));
            gemm(S2b, DD, owl, obl, S3b, DD, CH, DD, DD, 0);
            add_inorm<<<CH / 4, 256, 0, stream>>>(Xc, S3b);
            gemm(Xc, DD, w1l, b1l, S1b, FFD, CH, FFD, DD, 1);
            gemm(S1b, FFD, w2l, b2l, S3b, DD, CH, DD, FFD, 0);
            add_inorm<<<CH / 4, 256, 0, stream>>>(Xc, S3b);
        }
    }

    // ---- final: inorm over token-sum ----
    final_inorm<<<NSEQ / 4, 256, 0, stream>>>(Xb, out + NSEQ);
}

// Round 7
// 2387.740 us; speedup vs baseline: 5.9075x; 1.0370x over previous
//
#include <hip/hip_runtime.h>
#include <cstdint>
#include <cmath>

// ---------------- problem constants ----------------
#define DD      768
#define FFD     3072
#define NH      12
#define HDIM    64
#define LAYERS  3
#define CSZ     512
#define NB      256
#define NC      32
#define NSEQ    (NB * NC * 2)   // 16384 sequences
#define NTOK    (NSEQ * 2)      // 32768 token rows

typedef unsigned short ushort_t;
using short8 = __attribute__((ext_vector_type(8))) short;
using f32x4  = __attribute__((ext_vector_type(4))) float;

static __device__ __forceinline__ float b2f(ushort_t u) {
    union { float f; uint32_t i; } x; x.i = ((uint32_t)u) << 16; return x.f;
}
static __device__ __forceinline__ ushort_t f2b(float f) {
    uint32_t i = __float_as_uint(f);
    uint32_t r = (i + 0x7fffu + ((i >> 16) & 1u)) >> 16;   // RNE
    return (ushort_t)r;
}
static __device__ __forceinline__ float gelu_f(float x) {
    return 0.5f * x * (1.0f + erff(x * 0.70710678118654752f));
}
static __device__ __forceinline__ float wave_sum64(float v) {
#pragma unroll
    for (int off = 32; off > 0; off >>= 1) v += __shfl_xor(v, off, 64);
    return v;
}
static __device__ __forceinline__ void async_cp16(const void* g, void* l) {
    __builtin_amdgcn_global_load_lds((const __attribute__((address_space(1))) void*)g,
                                     (__attribute__((address_space(3))) void*)l, 16, 0, 0);
}
// raw workgroup barrier (does NOT drain vmcnt)
static __device__ __forceinline__ void wg_barrier() {
    asm volatile("" ::: "memory");
    __builtin_amdgcn_s_barrier();
    asm volatile("" ::: "memory");
}
#define WAITVM(N) asm volatile("s_waitcnt vmcnt(" #N ")" ::: "memory")
#define LDSFENCE() asm volatile("s_waitcnt lgkmcnt(0)" ::: "memory")

// ---------------- fp32 -> bf16 convert (n % 4 == 0) ----------------
__global__ __launch_bounds__(256) void cvt_bf16(const float* __restrict__ s,
                                                ushort_t* __restrict__ d, int n) {
    const int i = (blockIdx.x * 256 + threadIdx.x) * 4;
    if (i < n) {
        const float4 v = *(const float4*)(s + i);
        ushort4 o;
        o.x = f2b(v.x); o.y = f2b(v.y); o.z = f2b(v.z); o.w = f2b(v.w);
        *(ushort4*)(d + i) = o;
    }
}

// ---------------- build x0 (bf16): [32768][768] ----------------
__global__ __launch_bounds__(192) void build_x(const float* __restrict__ parent,
                                               const float* __restrict__ child,
                                               ushort_t* __restrict__ X) {
    const int r = blockIdx.x;
    const int t = threadIdx.x;        // 192 threads * 4 = 768
    const int n = r >> 1, q = r & 1;
    const int i = n >> 6;
    const int k = (n >> 1) & 31;
    const int j = n & 1;
    const float* src = (q == 0) ? (parent + (size_t)i * DD)
                                : (child + ((size_t)((i * 32 + k) * 2 + (1 - j))) * DD);
    const float4 v = ((const float4*)src)[t];
    ushort4 o;
    o.x = f2b(v.x); o.y = f2b(v.y); o.z = f2b(v.z); o.w = f2b(v.w);
    ((ushort4*)(X + (size_t)r * DD))[t] = o;
}

// ---------------- bf16 MFMA NT GEMM (legacy 128x128, used for small shapes) ----------------
__global__ __launch_bounds__(256) void gemm_bf16(const ushort_t* __restrict__ A, int lda,
                                                 const ushort_t* __restrict__ W,
                                                 const float* __restrict__ bias,
                                                 ushort_t* __restrict__ C, int ldc,
                                                 int K, int NT, int GM, int GN,
                                                 int dogelu) {
    __shared__ __align__(16) short smem[16384];   // 32 KB
    short* As = smem;
    short* Bs = smem + 8192;

    const int st = blockIdx.x / (GM * GN);
    const int stn = NT / GN;
    const int srow = st / stn, scol = st - srow * stn;
    const int r = blockIdx.x - st * (GM * GN);
    const int mt = srow * GM + r / GN;
    const int nt = scol * GN + (r - (r / GN) * GN);
    const int m0 = mt * 128;
    const int n0 = nt * 128;

    const int tid = threadIdx.x;
    const int r0s = tid >> 2, c0s = (tid & 3) * 8;
    const ushort_t* Ag0 = A + (size_t)(m0 + r0s) * lda + c0s;
    const ushort_t* Ag1 = A + (size_t)(m0 + 64 + r0s) * lda + c0s;
    const ushort_t* Wg0 = W + (size_t)(n0 + r0s) * K + c0s;
    const ushort_t* Wg1 = W + (size_t)(n0 + 64 + r0s) * K + c0s;

    const int wid = tid >> 6, lane = tid & 63;
    const int wm = (wid >> 1) * 64, wn = (wid & 1) * 64;
    const int lm = lane & 15;
    const int ko = (lane >> 4) * 8;

    f32x4 acc[4][4];
#pragma unroll
    for (int i = 0; i < 4; ++i)
#pragma unroll
        for (int j = 0; j < 4; ++j) acc[i][j] = {0.f, 0.f, 0.f, 0.f};

    {
        async_cp16(Ag0, As + tid * 8);
        async_cp16(Ag1, As + 2048 + tid * 8);
        async_cp16(Wg0, Bs + tid * 8);
        async_cp16(Wg1, Bs + 2048 + tid * 8);
    }

    for (int k0 = 0; k0 < K; k0 += 32) {
        const int b = (k0 >> 5) & 1;
        const int boff = b * 4096;
        __syncthreads();
        if (k0 + 32 < K) {
            const int o = (boff ^ 4096);
            const int k = k0 + 32;
            async_cp16(Ag0 + k, As + o + tid * 8);
            async_cp16(Ag1 + k, As + o + 2048 + tid * 8);
            async_cp16(Wg0 + k, Bs + o + tid * 8);
            async_cp16(Wg1 + k, Bs + o + 2048 + tid * 8);
        }
        short8 af[4], bfr[4];
#pragma unroll
        for (int i = 0; i < 4; ++i)
            af[i] = *(const short8*)(As + boff + (wm + i * 16 + lm) * 32 + ko);
#pragma unroll
        for (int j = 0; j < 4; ++j)
            bfr[j] = *(const short8*)(Bs + boff + (wn + j * 16 + lm) * 32 + ko);
#pragma unroll
        for (int i = 0; i < 4; ++i)
#pragma unroll
            for (int j = 0; j < 4; ++j)
                acc[i][j] = __builtin_amdgcn_mfma_f32_16x16x32_bf16(af[i], bfr[j], acc[i][j], 0, 0, 0);
    }

    float* T = (float*)smem;
    float* Tw = T + wid * 1088;
    const int r4 = lane >> 4;
    const int rrow = lane >> 2;
    const int rc0 = (lane & 3) * 16;
    const int gcolb = n0 + wn;

    float4 bb[4];
    if (bias) {
#pragma unroll
        for (int t = 0; t < 4; ++t) bb[t] = *(const float4*)(bias + gcolb + rc0 + t * 4);
    } else {
#pragma unroll
        for (int t = 0; t < 4; ++t) bb[t] = make_float4(0.f, 0.f, 0.f, 0.f);
    }

#pragma unroll
    for (int i = 0; i < 4; ++i) {
        __syncthreads();
#pragma unroll
        for (int j = 0; j < 4; ++j)
#pragma unroll
            for (int rr = 0; rr < 4; ++rr)
                Tw[(r4 * 4 + rr) * 68 + j * 16 + lm] = acc[i][j][rr];
        __syncthreads();
        float o[16];
#pragma unroll
        for (int t = 0; t < 4; ++t)
            *(f32x4*)&o[t * 4] = *(const f32x4*)(Tw + rrow * 68 + rc0 + t * 4);
#pragma unroll
        for (int t = 0; t < 4; ++t) {
            o[t * 4 + 0] += ((const float*)&bb[t])[0];
            o[t * 4 + 1] += ((const float*)&bb[t])[1];
            o[t * 4 + 2] += ((const float*)&bb[t])[2];
            o[t * 4 + 3] += ((const float*)&bb[t])[3];
        }
        if (dogelu) {
#pragma unroll
            for (int t = 0; t < 16; ++t) o[t] = gelu_f(o[t]);
        }
        uint32_t pk[8];
#pragma unroll
        for (int t = 0; t < 8; ++t)
            pk[t] = (uint32_t)f2b(o[2 * t]) | ((uint32_t)f2b(o[2 * t + 1]) << 16);
        ushort_t* dst = C + (size_t)(m0 + wm + i * 16 + rrow) * ldc + gcolb + rc0;
        *(uint4*)dst = make_uint4(pk[0], pk[1], pk[2], pk[3]);
        *(uint4*)(dst + 8) = make_uint4(pk[4], pk[5], pk[6], pk[7]);
    }
}

// ---------------- 128x256 8-wave GEMM, ring-3 counted-vmcnt, 2 blocks/CU ----------------
// C[M x N](bf16) = act( A[M x K](bf16, lda) @ W[N x K]^T + bias(f32) )
// Requirements: M%128==0, N%256==0, K%32==0, K>=96. Grid=(M/128)*(N/256), 512 thr.
// r4 baseline (2 blocks/CU, WAITVM(0) drain each K-step) = best so far; this adds T4:
// ring of 3 BK=32 buffers (3 x 24KB = 72KB -> still 2 blocks/CU), prefetch distance 2,
// steady-state s_waitcnt vmcnt(3): each iteration waits only for the tile staged TWO
// phases ago while the next tile's 3 loads stay in flight across the barrier. vmcnt
// never drains to 0 until the last tile. WAR safe: stage(s+2) overwrites buf (s-1)%3,
// whose reads retired (program order) before each wave crossed barrier s. RAW safe:
// each wave's own oldest-3 loads retired before barrier; barrier makes all visible.
// acc=64 + VGPR=64 => 128 regs/wave => 4 waves/SIMD ceiling (r5 ERRATA: forcing more
// spills acc to scratch). __launch_bounds__(512,4) pins that.
__global__ __launch_bounds__(512, 4) void gemm_mid(const ushort_t* __restrict__ A, int lda,
                                                   const ushort_t* __restrict__ W,
                                                   const float* __restrict__ bias,
                                                   ushort_t* __restrict__ C, int ldc,
                                                   int K, int NT, int GM, int GN,
                                                   int dogelu) {
    __shared__ __align__(16) short smem[36864];   // 72 KB: 3 x (A 8KB + B 16KB)
    const int tid = threadIdx.x;

    // ---- bijective XCD remap (m204), then supertile decode ----
    const int nwg = gridDim.x;
    const int bid = blockIdx.x;
    const int qx = nwg >> 3, rx = nwg & 7;
    const int xcd = bid & 7, pos = bid >> 3;
    const int wgid = (xcd < rx ? xcd * (qx + 1) : rx * (qx + 1) + (xcd - rx) * qx) + pos;
    const int stb = GM * GN;
    const int st = wgid / stb;
    const int stn = NT / GN;
    const int srow = st / stn, scol = st - srow * stn;
    const int r = wgid - st * stb;
    const int mt = srow * GM + r / GN;
    const int nt = scol * GN + (r - (r / GN) * GN);
    const int m0 = mt * 128, n0 = nt * 256;

    // ---- staging (pre-swizzled global source, linear LDS dest) ----
    const int srow_t = tid >> 2;                                  // 0..127
    const int scol_t = ((tid & 3) ^ ((tid >> 3) & 3)) << 3;       // swizzled col (elems)
    const ushort_t* Ag = A + (size_t)(m0 + srow_t) * lda + scol_t;
    const ushort_t* Bg = W + (size_t)(n0 + srow_t) * K + scol_t;
    const size_t ldbH = (size_t)128 * K;
    short* ldsA = smem + tid * 8;                 // A region: [0,4096) shorts per buf
    short* ldsB = smem + 4096 + tid * 8;          // B region: [4096,12288) per buf

    auto stage = [&](int bi_, int kt_) {          // stage K-step kt_ into ring buffer bi_
        const int b_ = bi_ * 12288;
        const int k_ = kt_ * 32;
        async_cp16(Ag + k_,        ldsA + b_);
        async_cp16(Bg + k_,        ldsB + b_);
        async_cp16(Bg + ldbH + k_, ldsB + b_ + 4096);
    };

    // ---- fragment read addresses (swizzled; same involution as staging) ----
    const int wid = tid >> 6, lane = tid & 63;
    const int wr = wid >> 2, wc = wid & 3;        // 2 x 4 wave grid; wave tile 64x64
    const int lm = lane & 15;
    const int swz = (((lane >> 4) ^ ((lane >> 1) & 3)) << 3);
    const short* rdA0 = smem + (wr * 64 + lm) * 32 + swz;
    const short* rdB0 = smem + 4096 + (wc * 64 + lm) * 32 + swz;

    f32x4 acc[4][4];
#pragma unroll
    for (int i = 0; i < 4; ++i)
#pragma unroll
        for (int j = 0; j < 4; ++j) acc[i][j] = {0.f, 0.f, 0.f, 0.f};

    const int NS = K >> 5;
    stage(0, 0);
    stage(1, 1);                  // 6 loads outstanding
    int bcur = 0;
    for (int s = 0; s < NS; ++s) {
        if (s < NS - 1) { WAITVM(3); }    // tile s arrived; tile s+1's 3 loads in flight
        else           { WAITVM(0); }
        wg_barrier();                      // tile s visible to all; buf (s-1)%3 reusable
        const int boff = bcur * 12288;
        short8 af[4], bf[4];
#pragma unroll
        for (int i = 0; i < 4; ++i) af[i] = *(const short8*)(rdA0 + boff + i * 512);
#pragma unroll
        for (int j = 0; j < 4; ++j) bf[j] = *(const short8*)(rdB0 + boff + j * 512);
        if (s + 2 < NS) {
            int bn = bcur + 2; if (bn >= 3) bn -= 3;
            stage(bn, s + 2);              // back to 6 outstanding
        }
#pragma unroll
        for (int i = 0; i < 4; ++i)
#pragma unroll
            for (int j = 0; j < 4; ++j)
                acc[i][j] = __builtin_amdgcn_mfma_f32_16x16x32_bf16(af[i], bf[j], acc[i][j], 0, 0, 0);
        bcur = (bcur == 2) ? 0 : bcur + 1;
    }
    wg_barrier();                  // epilogue Tw region overlaps staging buffers

    // ---- epilogue: per-wave-private LDS transpose -> uint4 bf16 stores ----
    float* Tw = (float*)smem + wid * 1088;        // 16*68 floats per wave (34.8 KB total)
    const int r4 = lane >> 4;
    const int rrow = lane >> 2;
    const int rc0 = (lane & 3) * 16;
    const int gcolb = n0 + wc * 64;

    float4 bb[4];
#pragma unroll
    for (int t = 0; t < 4; ++t) bb[t] = *(const float4*)(bias + gcolb + rc0 + t * 4);

#pragma unroll
    for (int mi = 0; mi < 4; ++mi) {
#pragma unroll
        for (int j = 0; j < 4; ++j)
#pragma unroll
            for (int rr = 0; rr < 4; ++rr)
                Tw[(r4 * 4 + rr) * 68 + j * 16 + lm] = acc[mi][j][rr];
        LDSFENCE();
        float o[16];
#pragma unroll
        for (int t = 0; t < 4; ++t)
            *(f32x4*)&o[t * 4] = *(const f32x4*)(Tw + rrow * 68 + rc0 + t * 4);
#pragma unroll
        for (int t = 0; t < 4; ++t) {
            o[t * 4 + 0] += ((const float*)&bb[t])[0];
            o[t * 4 + 1] += ((const float*)&bb[t])[1];
            o[t * 4 + 2] += ((const float*)&bb[t])[2];
            o[t * 4 + 3] += ((const float*)&bb[t])[3];
        }
        if (dogelu) {
#pragma unroll
            for (int t = 0; t < 16; ++t) o[t] = gelu_f(o[t]);
        }
        uint32_t pk[8];
#pragma unroll
        for (int t = 0; t < 8; ++t)
            pk[t] = (uint32_t)f2b(o[2 * t]) | ((uint32_t)f2b(o[2 * t + 1]) << 16);
        ushort_t* dst = C + (size_t)(m0 + wr * 64 + mi * 16 + rrow) * ldc + gcolb + rc0;
        *(uint4*)dst = make_uint4(pk[0], pk[1], pk[2], pk[3]);
        *(uint4*)(dst + 8) = make_uint4(pk[4], pk[5], pk[6], pk[7]);
        LDSFENCE();
    }
}

// ---------------- pe projections ----------------
__global__ __launch_bounds__(256) void pe_proj(const float* __restrict__ pel,
                                               const float* __restrict__ aiwl,
                                               float* __restrict__ PEQ,
                                               float* __restrict__ PEK) {
    const int wid = threadIdx.x >> 6, lane = threadIdx.x & 63;
    const int task = blockIdx.x * 4 + wid;
    const int which = task >= 3 * DD;
    const int idx = task - which * 3 * DD;
    const int r = idx / DD, o = idx - r * DD;
    const float* pe = pel + (size_t)r * DD;
    const float* w = aiwl + (size_t)(which ? DD + o : o) * DD;
    float s = 0.f;
#pragma unroll
    for (int e = 0; e < 12; ++e) s += pe[e * 64 + lane] * w[e * 64 + lane];
    s = wave_sum64(s);
    if (lane == 0) (which ? PEK : PEQ)[r * DD + o] = s;
}

// ---------------- attention (seq len 2), one wave per (sequence, head) ----------------
__global__ __launch_bounds__(256) void attn_kernel(const ushort_t* __restrict__ QKV,
                                                   const float* __restrict__ peq,
                                                   const float* __restrict__ pek,
                                                   ushort_t* __restrict__ O,
                                                   int seq0) {
    const int wid = threadIdx.x >> 6;
    const int lane = threadIdx.x & 63;
    const int task = blockIdx.x * 4 + wid;
    const int ns = task / NH;
    const int h = task - ns * NH;
    const int j = (seq0 + ns) & 1;
    const ushort_t* base = QKV + (size_t)(2 * ns) * (3 * DD);
    const int c = h * HDIM + lane;
    const int role1 = (1 + j) * DD;

    const float q0 = b2f(base[c]) + peq[c];
    const float k0 = b2f(base[DD + c]) + pek[c];
    const float v0 = b2f(base[2 * DD + c]);
    const ushort_t* base1 = base + 3 * DD;
    const float q1 = b2f(base1[c]) + peq[role1 + c];
    const float k1 = b2f(base1[DD + c]) + pek[role1 + c];
    const float v1 = b2f(base1[2 * DD + c]);

    float p00 = q0 * k0, p01 = q0 * k1, p10 = q1 * k0, p11 = q1 * k1;
#pragma unroll
    for (int off = 32; off > 0; off >>= 1) {
        p00 += __shfl_xor(p00, off, 64);
        p01 += __shfl_xor(p01, off, 64);
        p10 += __shfl_xor(p10, off, 64);
        p11 += __shfl_xor(p11, off, 64);
    }
    const float sc = 0.125f;
    const float s00 = p00 * sc, s01 = p01 * sc, s10 = p10 * sc, s11 = p11 * sc;

    const float m0 = fmaxf(s00, s01);
    const float e00 = __expf(s00 - m0), e01 = __expf(s01 - m0);
    const float a00 = e00 / (e00 + e01);
    const float o0 = a00 * v0 + (1.0f - a00) * v1;

    const float m1 = fmaxf(s10, s11);
    const float e10 = __expf(s10 - m1), e11 = __expf(s11 - m1);
    const float a10 = e10 / (e10 + e11);
    const float o1 = a10 * v0 + (1.0f - a10) * v1;

    O[(size_t)(2 * ns) * DD + c] = f2b(o0);
    O[(size_t)(2 * ns + 1) * DD + c] = f2b(o1);
}

// ---------------- x = inorm(x + d), bf16 in/out, one wave per row ----------------
__global__ __launch_bounds__(256) void add_inorm(ushort_t* __restrict__ x,
                                                 const ushort_t* __restrict__ d) {
    const int wid = threadIdx.x >> 6, lane = threadIdx.x & 63;
    const int r = blockIdx.x * 4 + wid;
    ushort_t* xr = x + (size_t)r * DD;
    const ushort_t* dr = d + (size_t)r * DD;
    float v[12];
    float s = 0.f, ss = 0.f;
#pragma unroll
    for (int e = 0; e < 3; ++e) {
        const ushort4 xa = ((const ushort4*)xr)[e * 64 + lane];
        const ushort4 da = ((const ushort4*)dr)[e * 64 + lane];
        const float a0 = b2f(xa.x) + b2f(da.x);
        const float a1 = b2f(xa.y) + b2f(da.y);
        const float a2 = b2f(xa.z) + b2f(da.z);
        const float a3 = b2f(xa.w) + b2f(da.w);
        v[e * 4 + 0] = a0; v[e * 4 + 1] = a1; v[e * 4 + 2] = a2; v[e * 4 + 3] = a3;
        s += a0 + a1 + a2 + a3;
        ss += a0 * a0 + a1 * a1 + a2 * a2 + a3 * a3;
    }
    s = wave_sum64(s); ss = wave_sum64(ss);
    const float mean = s * (1.0f / DD);
    const float var = ss * (1.0f / DD) - mean * mean;
    const float rs = rsqrtf(var + 1e-5f);
#pragma unroll
    for (int e = 0; e < 3; ++e) {
        ushort4 o;
        o.x = f2b((v[e * 4 + 0] - mean) * rs);
        o.y = f2b((v[e * 4 + 1] - mean) * rs);
        o.z = f2b((v[e * 4 + 2] - mean) * rs);
        o.w = f2b((v[e * 4 + 3] - mean) * rs);
        ((ushort4*)xr)[e * 64 + lane] = o;
    }
}

// ---------------- final: out[n] = inorm(x[2n] + x[2n+1]) fp32 out ----------------
__global__ __launch_bounds__(256) void final_inorm(const ushort_t* __restrict__ x,
                                                   float* __restrict__ out) {
    const int wid = threadIdx.x >> 6, lane = threadIdx.x & 63;
    const int n = blockIdx.x * 4 + wid;
    const ushort_t* r0 = x + (size_t)(2 * n) * DD;
    const ushort_t* r1 = r0 + DD;
    float v[12];
    float s = 0.f, ss = 0.f;
#pragma unroll
    for (int e = 0; e < 3; ++e) {
        const ushort4 xa = ((const ushort4*)r0)[e * 64 + lane];
        const ushort4 xb = ((const ushort4*)r1)[e * 64 + lane];
        const float a0 = b2f(xa.x) + b2f(xb.x);
        const float a1 = b2f(xa.y) + b2f(xb.y);
        const float a2 = b2f(xa.z) + b2f(xb.z);
        const float a3 = b2f(xa.w) + b2f(xb.w);
        v[e * 4 + 0] = a0; v[e * 4 + 1] = a1; v[e * 4 + 2] = a2; v[e * 4 + 3] = a3;
        s += a0 + a1 + a2 + a3;
        ss += a0 * a0 + a1 * a1 + a2 * a2 + a3 * a3;
    }
    s = wave_sum64(s); ss = wave_sum64(ss);
    const float mean = s * (1.0f / DD);
    const float var = ss * (1.0f / DD) - mean * mean;
    const float rs = rsqrtf(var + 1e-5f);
    float* orow = out + (size_t)n * DD;
#pragma unroll
    for (int e = 0; e < 3; ++e) {
        float4 o;
        o.x = (v[e * 4 + 0] - mean) * rs;
        o.y = (v[e * 4 + 1] - mean) * rs;
        o.z = (v[e * 4 + 2] - mean) * rs;
        o.w = (v[e * 4 + 3] - mean) * rs;
        ((float4*)orow)[e * 64 + lane] = o;
    }
}

// ---------------- scores ----------------
__global__ __launch_bounds__(256) void score_dot(const ushort_t* __restrict__ pc,
                                                 const ushort_t* __restrict__ cc,
                                                 float* __restrict__ out, int which) {
    const int wid = threadIdx.x >> 6;
    const int lane = threadIdx.x & 63;
    const int row = blockIdx.x * 4 + wid;
    const int b = row >> 5;
    const ushort_t* p = pc + (size_t)b * CSZ;
    const ushort_t* c = cc + (size_t)row * CSZ;
    float s = 0.f;
#pragma unroll
    for (int e = 0; e < 8; ++e) s += b2f(p[e * 64 + lane]) * b2f(c[e * 64 + lane]);
    s = wave_sum64(s);
    if (lane == 0) out[row * 2 + which] = s * 0.04419417382415922f; // 1/sqrt(512)
}

// ---------------- host launch ----------------
extern "C" void kernel_launch(void* const* d_in, const int* in_sizes, int n_in,
                              void* d_out, int out_size, void* d_ws, size_t ws_size,
                              hipStream_t stream) {
    const float* parent = (const float*)d_in[0];
    const float* child  = (const float*)d_in[1];
    const float* aiw = (const float*)d_in[4];
    const float* aib = (const float*)d_in[5];
    const float* aow = (const float*)d_in[6];
    const float* aob = (const float*)d_in[7];
    const float* l1w = (const float*)d_in[8];
    const float* l1b = (const float*)d_in[9];
    const float* l2w = (const float*)d_in[10];
    const float* l2b = (const float*)d_in[11];
    const float* pemb = (const float*)d_in[12];
    const float* pw1 = (const float*)d_in[13];
    const float* pb1 = (const float*)d_in[14];
    const float* pw2 = (const float*)d_in[15];
    const float* pb2 = (const float*)d_in[16];
    const float* lw1 = (const float*)d_in[17];
    const float* lb1 = (const float*)d_in[18];
    const float* lw2 = (const float*)d_in[19];
    const float* lb2 = (const float*)d_in[20];
    const float* rw1 = (const float*)d_in[21];
    const float* rb1 = (const float*)d_in[22];
    const float* rw2 = (const float*)d_in[23];
    const float* rb2 = (const float*)d_in[24];
    float* out = (float*)d_out;
    (void)in_sizes; (void)n_in; (void)out_size;

    // ---- pick chunk rows from workspace ----
    int CH = 8192;
    {
        const size_t fixedB = 100ull * 1024 * 1024;
        if (ws_size >= fixedB + (size_t)32768 * 4608 * 2) CH = 32768;
        else if (ws_size >= fixedB + (size_t)16384 * 4608 * 2) CH = 16384;
    }
    const int NCH = NTOK / CH;

    ushort_t* W0 = (ushort_t*)d_ws;
    size_t off = 0;
    auto take = [&](size_t elems) { ushort_t* p = W0 + off; off += (elems + 127) & ~(size_t)127; return p; };
    ushort_t* aiw_b = take((size_t)LAYERS * 3 * DD * DD);
    ushort_t* aow_b = take((size_t)LAYERS * DD * DD);
    ushort_t* l1w_b = take((size_t)LAYERS * FFD * DD);
    ushort_t* l2w_b = take((size_t)LAYERS * DD * FFD);
    ushort_t* pw1_b = take((size_t)DD * DD);
    ushort_t* pw2_b = take((size_t)CSZ * DD);
    ushort_t* lw1_b = take((size_t)DD * DD);
    ushort_t* lw2_b = take((size_t)CSZ * DD);
    ushort_t* rw1_b = take((size_t)DD * DD);
    ushort_t* rw2_b = take((size_t)CSZ * DD);
    ushort_t* Pb    = take((size_t)NB * DD);
    ushort_t* Xb    = take((size_t)NTOK * DD);
    ushort_t* S1b   = take((size_t)CH * FFD);
    ushort_t* S2b   = take((size_t)CH * DD);
    ushort_t* S3b   = take((size_t)CH * DD);
    ushort_t* P1b   = take((size_t)NB * DD);
    ushort_t* P2b   = take((size_t)NB * CSZ);
    float* PEQ = (float*)(W0 + off); off += 2 * 3 * DD;
    float* PEK = PEQ + 3 * DD;

    auto cvt = [&](const float* s, ushort_t* d, size_t n) {
        cvt_bf16<<<(int)((n + 1023) / 1024), 256, 0, stream>>>(s, d, (int)n);
    };
    auto gemm = [&](const ushort_t* A, int lda, const ushort_t* Wt, const float* bias,
                    ushort_t* C, int ldc, int M, int N, int K, int dg) {
        if (M % 128 == 0 && N % 256 == 0 && M >= 8192 && K >= 96 && K % 32 == 0) {
            const int MT = M / 128, NT = N / 256;
            const int GM = (MT % 8 == 0) ? 8 : ((MT % 4 == 0) ? 4 : MT);
            int GN = 8;
            while (NT % GN) --GN;
            gemm_mid<<<MT * NT, 512, 0, stream>>>(A, lda, Wt, bias, C, ldc, K, NT, GM, GN, dg);
        } else {
            const int MT = M / 128, NT = N / 128;
            const int GM = (MT % 8 == 0) ? 8 : MT;
            int GN = 8;
            while (NT % GN) --GN;
            gemm_bf16<<<MT * NT, 256, 0, stream>>>(A, lda, Wt, bias, C, ldc, K, NT, GM, GN, dg);
        }
    };

    // ---- weight / input conversions ----
    cvt(aiw, aiw_b, (size_t)LAYERS * 3 * DD * DD);
    cvt(aow, aow_b, (size_t)LAYERS * DD * DD);
    cvt(l1w, l1w_b, (size_t)LAYERS * FFD * DD);
    cvt(l2w, l2w_b, (size_t)LAYERS * DD * FFD);
    cvt(pw1, pw1_b, (size_t)DD * DD);
    cvt(pw2, pw2_b, (size_t)CSZ * DD);
    cvt(lw1, lw1_b, (size_t)DD * DD);
    cvt(lw2, lw2_b, (size_t)CSZ * DD);
    cvt(rw1, rw1_b, (size_t)DD * DD);
    cvt(rw2, rw2_b, (size_t)CSZ * DD);
    cvt(parent, Pb, (size_t)NB * DD);
    cvt(child, S1b, (size_t)NB * NC * 2 * DD);   // child bf16 into S1b [16384][768]

    // ---- build x0 ----
    build_x<<<NTOK, 192, 0, stream>>>(parent, child, Xb);

    // ---- outside scores ----
    gemm(Pb, DD, pw1_b, pb1, P1b, DD, NB, DD, DD, 1);
    gemm(P1b, DD, pw2_b, pb2, P2b, CSZ, NB, CSZ, DD, 0);
    gemm(S1b, 2 * DD, lw1_b, lb1, S2b, DD, NB * NC, DD, DD, 1);
    gemm(S2b, DD, lw2_b, lb2, S3b, CSZ, NB * NC, CSZ, DD, 0);
    score_dot<<<NB * NC / 4, 256, 0, stream>>>(P2b, S3b, out, 1);
    gemm(S1b + DD, 2 * DD, rw1_b, rb1, S2b, DD, NB * NC, DD, DD, 1);
    gemm(S2b, DD, rw2_b, rb2, S3b, CSZ, NB * NC, CSZ, DD, 0);
    score_dot<<<NB * NC / 4, 256, 0, stream>>>(P2b, S3b, out, 0);

    // ---- transformer layers ----
    for (int l = 0; l < LAYERS; ++l) {
        const ushort_t* Wl  = aiw_b + (size_t)l * 3 * DD * DD;
        const float* bl  = aib + (size_t)l * 3 * DD;
        const ushort_t* owl = aow_b + (size_t)l * DD * DD;
        const float* obl = aob + (size_t)l * DD;
        const ushort_t* w1l = l1w_b + (size_t)l * FFD * DD;
        const float* b1l = l1b + (size_t)l * FFD;
        const ushort_t* w2l = l2w_b + (size_t)l * DD * FFD;
        const float* b2l = l2b + (size_t)l * DD;

        pe_proj<<<2 * 3 * DD / 4, 256, 0, stream>>>(pemb + (size_t)l * 4 * DD,
                                                    aiw + (size_t)l * 3 * DD * DD, PEQ, PEK);

        for (int c = 0; c < NCH; ++c) {
            ushort_t* Xc = Xb + (size_t)c * CH * DD;
            gemm(Xc, DD, Wl, bl, S1b, 3 * DD, CH, 3 * DD, DD, 0);
            attn_kernel<<<(CH / 2) * NH / 4, 256, 0, stream>>>(S1b, PEQ, PEK, S2b, c * (CH / 2));
            gemm(S2b, DD, owl, obl, S3b, DD, CH, DD, DD, 0);
            add_inorm<<<CH / 4, 256, 0, stream>>>(Xc, S3b);
            gemm(Xc, DD, w1l, b1l, S1b, FFD, CH, FFD, DD, 1);
            gemm(S1b, FFD, w2l, b2l, S3b, DD, CH, DD, FFD, 0);
            add_inorm<<<CH / 4, 256, 0, stream>>>(Xc, S3b);
        }
    }

    // ---- final: inorm over token-sum ----
    final_inorm<<<NSEQ / 4, 256, 0, stream>>>(Xb, out + NSEQ);
}

// Round 8
// 2372.883 us; speedup vs baseline: 5.9445x; 1.0063x over previous
//
#include <hip/hip_runtime.h>
#include <cstdint>
#include <cmath>

// ---------------- problem constants ----------------
#define DD      768
#define FFD     3072
#define NH      12
#define HDIM    64
#define LAYERS  3
#define CSZ     512
#define NB      256
#define NC      32
#define NSEQ    (NB * NC * 2)   // 16384 sequences
#define NTOK    (NSEQ * 2)      // 32768 token rows

typedef unsigned short ushort_t;
using short8 = __attribute__((ext_vector_type(8))) short;
using f32x4  = __attribute__((ext_vector_type(4))) float;

static __device__ __forceinline__ float b2f(ushort_t u) {
    union { float f; uint32_t i; } x; x.i = ((uint32_t)u) << 16; return x.f;
}
static __device__ __forceinline__ ushort_t f2b(float f) {
    uint32_t i = __float_as_uint(f);
    uint32_t r = (i + 0x7fffu + ((i >> 16) & 1u)) >> 16;   // RNE
    return (ushort_t)r;
}
static __device__ __forceinline__ float gelu_f(float x) {
    return 0.5f * x * (1.0f + erff(x * 0.70710678118654752f));
}
static __device__ __forceinline__ float wave_sum64(float v) {
#pragma unroll
    for (int off = 32; off > 0; off >>= 1) v += __shfl_xor(v, off, 64);
    return v;
}
static __device__ __forceinline__ void async_cp16(const void* g, void* l) {
    __builtin_amdgcn_global_load_lds((const __attribute__((address_space(1))) void*)g,
                                     (__attribute__((address_space(3))) void*)l, 16, 0, 0);
}
// raw workgroup barrier (does NOT drain vmcnt)
static __device__ __forceinline__ void wg_barrier() {
    asm volatile("" ::: "memory");
    __builtin_amdgcn_s_barrier();
    asm volatile("" ::: "memory");
}
#define WAITVM(N) asm volatile("s_waitcnt vmcnt(" #N ")" ::: "memory")
#define LDSFENCE() asm volatile("s_waitcnt lgkmcnt(0)" ::: "memory")

// ---------------- fp32 -> bf16 convert (n % 4 == 0) ----------------
__global__ __launch_bounds__(256) void cvt_bf16(const float* __restrict__ s,
                                                ushort_t* __restrict__ d, int n) {
    const int i = (blockIdx.x * 256 + threadIdx.x) * 4;
    if (i < n) {
        const float4 v = *(const float4*)(s + i);
        ushort4 o;
        o.x = f2b(v.x); o.y = f2b(v.y); o.z = f2b(v.z); o.w = f2b(v.w);
        *(ushort4*)(d + i) = o;
    }
}

// ---------------- packed small converts: parent + 6 MLP weights (1 launch) ----------------
// Segment sizes (in float4 chunks): parent 49152 | w1 147456 | w2 98304 (x3 pairs).
// Total 786432 chunks -> grid 3072 x 256.
__global__ __launch_bounds__(256) void cvt_small(const float* __restrict__ p,  ushort_t* __restrict__ pd,
                                                 const float* __restrict__ a0, ushort_t* __restrict__ a0d,
                                                 const float* __restrict__ a1, ushort_t* __restrict__ a1d,
                                                 const float* __restrict__ b0, ushort_t* __restrict__ b0d,
                                                 const float* __restrict__ b1, ushort_t* __restrict__ b1d,
                                                 const float* __restrict__ c0, ushort_t* __restrict__ c0d,
                                                 const float* __restrict__ c1, ushort_t* __restrict__ c1d) {
    const int ch = blockIdx.x * 256 + threadIdx.x;
    const float* s; ushort_t* d; int base;
    if      (ch < 49152)  { s = p;  d = pd;  base = 0; }
    else if (ch < 196608) { s = a0; d = a0d; base = 49152; }
    else if (ch < 294912) { s = a1; d = a1d; base = 196608; }
    else if (ch < 442368) { s = b0; d = b0d; base = 294912; }
    else if (ch < 540672) { s = b1; d = b1d; base = 442368; }
    else if (ch < 688128) { s = c0; d = c0d; base = 540672; }
    else                  { s = c1; d = c1d; base = 688128; }
    const int i = (ch - base) * 4;
    const float4 v = *(const float4*)(s + i);
    ushort4 o;
    o.x = f2b(v.x); o.y = f2b(v.y); o.z = f2b(v.z); o.w = f2b(v.w);
    *(ushort4*)(d + i) = o;
}

// ---------------- build x0 (bf16): [32768][768] ----------------
__global__ __launch_bounds__(192) void build_x(const float* __restrict__ parent,
                                               const float* __restrict__ child,
                                               ushort_t* __restrict__ X) {
    const int r = blockIdx.x;
    const int t = threadIdx.x;        // 192 threads * 4 = 768
    const int n = r >> 1, q = r & 1;
    const int i = n >> 6;
    const int k = (n >> 1) & 31;
    const int j = n & 1;
    const float* src = (q == 0) ? (parent + (size_t)i * DD)
                                : (child + ((size_t)((i * 32 + k) * 2 + (1 - j))) * DD);
    const float4 v = ((const float4*)src)[t];
    ushort4 o;
    o.x = f2b(v.x); o.y = f2b(v.y); o.z = f2b(v.z); o.w = f2b(v.w);
    ((ushort4*)(X + (size_t)r * DD))[t] = o;
}

// ---------------- bf16 MFMA NT GEMM (legacy 128x128, used for small shapes) ----------------
__global__ __launch_bounds__(256) void gemm_bf16(const ushort_t* __restrict__ A, int lda,
                                                 const ushort_t* __restrict__ W,
                                                 const float* __restrict__ bias,
                                                 ushort_t* __restrict__ C, int ldc,
                                                 int K, int NT, int GM, int GN,
                                                 int dogelu) {
    __shared__ __align__(16) short smem[16384];   // 32 KB
    short* As = smem;
    short* Bs = smem + 8192;

    const int st = blockIdx.x / (GM * GN);
    const int stn = NT / GN;
    const int srow = st / stn, scol = st - srow * stn;
    const int r = blockIdx.x - st * (GM * GN);
    const int mt = srow * GM + r / GN;
    const int nt = scol * GN + (r - (r / GN) * GN);
    const int m0 = mt * 128;
    const int n0 = nt * 128;

    const int tid = threadIdx.x;
    const int r0s = tid >> 2, c0s = (tid & 3) * 8;
    const ushort_t* Ag0 = A + (size_t)(m0 + r0s) * lda + c0s;
    const ushort_t* Ag1 = A + (size_t)(m0 + 64 + r0s) * lda + c0s;
    const ushort_t* Wg0 = W + (size_t)(n0 + r0s) * K + c0s;
    const ushort_t* Wg1 = W + (size_t)(n0 + 64 + r0s) * K + c0s;

    const int wid = tid >> 6, lane = tid & 63;
    const int wm = (wid >> 1) * 64, wn = (wid & 1) * 64;
    const int lm = lane & 15;
    const int ko = (lane >> 4) * 8;

    f32x4 acc[4][4];
#pragma unroll
    for (int i = 0; i < 4; ++i)
#pragma unroll
        for (int j = 0; j < 4; ++j) acc[i][j] = {0.f, 0.f, 0.f, 0.f};

    {
        async_cp16(Ag0, As + tid * 8);
        async_cp16(Ag1, As + 2048 + tid * 8);
        async_cp16(Wg0, Bs + tid * 8);
        async_cp16(Wg1, Bs + 2048 + tid * 8);
    }

    for (int k0 = 0; k0 < K; k0 += 32) {
        const int b = (k0 >> 5) & 1;
        const int boff = b * 4096;
        __syncthreads();
        if (k0 + 32 < K) {
            const int o = (boff ^ 4096);
            const int k = k0 + 32;
            async_cp16(Ag0 + k, As + o + tid * 8);
            async_cp16(Ag1 + k, As + o + 2048 + tid * 8);
            async_cp16(Wg0 + k, Bs + o + tid * 8);
            async_cp16(Wg1 + k, Bs + o + 2048 + tid * 8);
        }
        short8 af[4], bfr[4];
#pragma unroll
        for (int i = 0; i < 4; ++i)
            af[i] = *(const short8*)(As + boff + (wm + i * 16 + lm) * 32 + ko);
#pragma unroll
        for (int j = 0; j < 4; ++j)
            bfr[j] = *(const short8*)(Bs + boff + (wn + j * 16 + lm) * 32 + ko);
#pragma unroll
        for (int i = 0; i < 4; ++i)
#pragma unroll
            for (int j = 0; j < 4; ++j)
                acc[i][j] = __builtin_amdgcn_mfma_f32_16x16x32_bf16(af[i], bfr[j], acc[i][j], 0, 0, 0);
    }

    float* T = (float*)smem;
    float* Tw = T + wid * 1088;
    const int r4 = lane >> 4;
    const int rrow = lane >> 2;
    const int rc0 = (lane & 3) * 16;
    const int gcolb = n0 + wn;

    float4 bb[4];
    if (bias) {
#pragma unroll
        for (int t = 0; t < 4; ++t) bb[t] = *(const float4*)(bias + gcolb + rc0 + t * 4);
    } else {
#pragma unroll
        for (int t = 0; t < 4; ++t) bb[t] = make_float4(0.f, 0.f, 0.f, 0.f);
    }

#pragma unroll
    for (int i = 0; i < 4; ++i) {
        __syncthreads();
#pragma unroll
        for (int j = 0; j < 4; ++j)
#pragma unroll
            for (int rr = 0; rr < 4; ++rr)
                Tw[(r4 * 4 + rr) * 68 + j * 16 + lm] = acc[i][j][rr];
        __syncthreads();
        float o[16];
#pragma unroll
        for (int t = 0; t < 4; ++t)
            *(f32x4*)&o[t * 4] = *(const f32x4*)(Tw + rrow * 68 + rc0 + t * 4);
#pragma unroll
        for (int t = 0; t < 4; ++t) {
            o[t * 4 + 0] += ((const float*)&bb[t])[0];
            o[t * 4 + 1] += ((const float*)&bb[t])[1];
            o[t * 4 + 2] += ((const float*)&bb[t])[2];
            o[t * 4 + 3] += ((const float*)&bb[t])[3];
        }
        if (dogelu) {
#pragma unroll
            for (int t = 0; t < 16; ++t) o[t] = gelu_f(o[t]);
        }
        uint32_t pk[8];
#pragma unroll
        for (int t = 0; t < 8; ++t)
            pk[t] = (uint32_t)f2b(o[2 * t]) | ((uint32_t)f2b(o[2 * t + 1]) << 16);
        ushort_t* dst = C + (size_t)(m0 + wm + i * 16 + rrow) * ldc + gcolb + rc0;
        *(uint4*)dst = make_uint4(pk[0], pk[1], pk[2], pk[3]);
        *(uint4*)(dst + 8) = make_uint4(pk[4], pk[5], pk[6], pk[7]);
    }
}

// ---------------- 128x256 8-wave GEMM, ring-3 counted-vmcnt, 2 blocks/CU ----------------
// C[M x N](bf16) = act( A[M x K](bf16, lda) @ W[N x K]^T + bias(f32) ) [+ resid (bf16)]
// Requirements: M%128==0, N%256==0, K%32==0, K>=96. Grid=(M/128)*(N/256), 512 thr.
// Ring of 3 BK=32 buffers (72KB -> 2 blocks/CU), prefetch distance 2, steady-state
// s_waitcnt vmcnt(3) (never drains to 0 until the last tile). acc=64 + VGPR=64 =>
// 128 regs/wave => 4 waves/SIMD ceiling (r5 ERRATA: forcing more spills acc to scratch).
// resid != nullptr: epilogue adds the bf16 residual tile (same ld as C) before packing
// -- fuses the residual-add pass of x = inorm(x + d) into the GEMM.
__global__ __launch_bounds__(512, 4) void gemm_mid(const ushort_t* __restrict__ A, int lda,
                                                   const ushort_t* __restrict__ W,
                                                   const float* __restrict__ bias,
                                                   ushort_t* __restrict__ C, int ldc,
                                                   int K, int NT, int GM, int GN,
                                                   int dogelu,
                                                   const ushort_t* __restrict__ resid) {
    __shared__ __align__(16) short smem[36864];   // 72 KB: 3 x (A 8KB + B 16KB)
    const int tid = threadIdx.x;

    // ---- bijective XCD remap (m204), then supertile decode ----
    const int nwg = gridDim.x;
    const int bid = blockIdx.x;
    const int qx = nwg >> 3, rx = nwg & 7;
    const int xcd = bid & 7, pos = bid >> 3;
    const int wgid = (xcd < rx ? xcd * (qx + 1) : rx * (qx + 1) + (xcd - rx) * qx) + pos;
    const int stb = GM * GN;
    const int st = wgid / stb;
    const int stn = NT / GN;
    const int srow = st / stn, scol = st - srow * stn;
    const int r = wgid - st * stb;
    const int mt = srow * GM + r / GN;
    const int nt = scol * GN + (r - (r / GN) * GN);
    const int m0 = mt * 128, n0 = nt * 256;

    // ---- staging (pre-swizzled global source, linear LDS dest) ----
    const int srow_t = tid >> 2;                                  // 0..127
    const int scol_t = ((tid & 3) ^ ((tid >> 3) & 3)) << 3;       // swizzled col (elems)
    const ushort_t* Ag = A + (size_t)(m0 + srow_t) * lda + scol_t;
    const ushort_t* Bg = W + (size_t)(n0 + srow_t) * K + scol_t;
    const size_t ldbH = (size_t)128 * K;
    short* ldsA = smem + tid * 8;                 // A region: [0,4096) shorts per buf
    short* ldsB = smem + 4096 + tid * 8;          // B region: [4096,12288) per buf

    auto stage = [&](int bi_, int kt_) {          // stage K-step kt_ into ring buffer bi_
        const int b_ = bi_ * 12288;
        const int k_ = kt_ * 32;
        async_cp16(Ag + k_,        ldsA + b_);
        async_cp16(Bg + k_,        ldsB + b_);
        async_cp16(Bg + ldbH + k_, ldsB + b_ + 4096);
    };

    // ---- fragment read addresses (swizzled; same involution as staging) ----
    const int wid = tid >> 6, lane = tid & 63;
    const int wr = wid >> 2, wc = wid & 3;        // 2 x 4 wave grid; wave tile 64x64
    const int lm = lane & 15;
    const int swz = (((lane >> 4) ^ ((lane >> 1) & 3)) << 3);
    const short* rdA0 = smem + (wr * 64 + lm) * 32 + swz;
    const short* rdB0 = smem + 4096 + (wc * 64 + lm) * 32 + swz;

    f32x4 acc[4][4];
#pragma unroll
    for (int i = 0; i < 4; ++i)
#pragma unroll
        for (int j = 0; j < 4; ++j) acc[i][j] = {0.f, 0.f, 0.f, 0.f};

    const int NS = K >> 5;
    stage(0, 0);
    stage(1, 1);                  // 6 loads outstanding
    int bcur = 0;
    for (int s = 0; s < NS; ++s) {
        if (s < NS - 1) { WAITVM(3); }    // tile s arrived; tile s+1's 3 loads in flight
        else           { WAITVM(0); }
        wg_barrier();                      // tile s visible to all; buf (s-1)%3 reusable
        const int boff = bcur * 12288;
        short8 af[4], bf[4];
#pragma unroll
        for (int i = 0; i < 4; ++i) af[i] = *(const short8*)(rdA0 + boff + i * 512);
#pragma unroll
        for (int j = 0; j < 4; ++j) bf[j] = *(const short8*)(rdB0 + boff + j * 512);
        if (s + 2 < NS) {
            int bn = bcur + 2; if (bn >= 3) bn -= 3;
            stage(bn, s + 2);              // back to 6 outstanding
        }
#pragma unroll
        for (int i = 0; i < 4; ++i)
#pragma unroll
            for (int j = 0; j < 4; ++j)
                acc[i][j] = __builtin_amdgcn_mfma_f32_16x16x32_bf16(af[i], bf[j], acc[i][j], 0, 0, 0);
        bcur = (bcur == 2) ? 0 : bcur + 1;
    }
    wg_barrier();                  // epilogue Tw region overlaps staging buffers

    // ---- epilogue: per-wave-private LDS transpose -> uint4 bf16 stores ----
    float* Tw = (float*)smem + wid * 1088;        // 16*68 floats per wave (34.8 KB total)
    const int r4 = lane >> 4;
    const int rrow = lane >> 2;
    const int rc0 = (lane & 3) * 16;
    const int gcolb = n0 + wc * 64;

    float4 bb[4];
#pragma unroll
    for (int t = 0; t < 4; ++t) bb[t] = *(const float4*)(bias + gcolb + rc0 + t * 4);

#pragma unroll
    for (int mi = 0; mi < 4; ++mi) {
#pragma unroll
        for (int j = 0; j < 4; ++j)
#pragma unroll
            for (int rr = 0; rr < 4; ++rr)
                Tw[(r4 * 4 + rr) * 68 + j * 16 + lm] = acc[mi][j][rr];
        LDSFENCE();
        float o[16];
#pragma unroll
        for (int t = 0; t < 4; ++t)
            *(f32x4*)&o[t * 4] = *(const f32x4*)(Tw + rrow * 68 + rc0 + t * 4);
#pragma unroll
        for (int t = 0; t < 4; ++t) {
            o[t * 4 + 0] += ((const float*)&bb[t])[0];
            o[t * 4 + 1] += ((const float*)&bb[t])[1];
            o[t * 4 + 2] += ((const float*)&bb[t])[2];
            o[t * 4 + 3] += ((const float*)&bb[t])[3];
        }
        if (dogelu) {
#pragma unroll
            for (int t = 0; t < 16; ++t) o[t] = gelu_f(o[t]);
        }
        const size_t rowoff = (size_t)(m0 + wr * 64 + mi * 16 + rrow) * ldc + gcolb + rc0;
        if (resid) {                                  // fused residual add (f32 sum)
            const uint4 ra = *(const uint4*)(resid + rowoff);
            const uint4 rb = *(const uint4*)(resid + rowoff + 8);
            const uint32_t rw[8] = {ra.x, ra.y, ra.z, ra.w, rb.x, rb.y, rb.z, rb.w};
#pragma unroll
            for (int t = 0; t < 8; ++t) {
                o[2 * t]     += b2f((ushort_t)(rw[t] & 0xffffu));
                o[2 * t + 1] += b2f((ushort_t)(rw[t] >> 16));
            }
        }
        uint32_t pk[8];
#pragma unroll
        for (int t = 0; t < 8; ++t)
            pk[t] = (uint32_t)f2b(o[2 * t]) | ((uint32_t)f2b(o[2 * t + 1]) << 16);
        ushort_t* dst = C + rowoff;
        *(uint4*)dst = make_uint4(pk[0], pk[1], pk[2], pk[3]);
        *(uint4*)(dst + 8) = make_uint4(pk[4], pk[5], pk[6], pk[7]);
        LDSFENCE();
    }
}

// ---------------- pe projections ----------------
__global__ __launch_bounds__(256) void pe_proj(const float* __restrict__ pel,
                                               const float* __restrict__ aiwl,
                                               float* __restrict__ PEQ,
                                               float* __restrict__ PEK) {
    const int wid = threadIdx.x >> 6, lane = threadIdx.x & 63;
    const int task = blockIdx.x * 4 + wid;
    const int which = task >= 3 * DD;
    const int idx = task - which * 3 * DD;
    const int r = idx / DD, o = idx - r * DD;
    const float* pe = pel + (size_t)r * DD;
    const float* w = aiwl + (size_t)(which ? DD + o : o) * DD;
    float s = 0.f;
#pragma unroll
    for (int e = 0; e < 12; ++e) s += pe[e * 64 + lane] * w[e * 64 + lane];
    s = wave_sum64(s);
    if (lane == 0) (which ? PEK : PEQ)[r * DD + o] = s;
}

// ---------------- attention (seq len 2), one wave per (sequence, head) ----------------
__global__ __launch_bounds__(256) void attn_kernel(const ushort_t* __restrict__ QKV,
                                                   const float* __restrict__ peq,
                                                   const float* __restrict__ pek,
                                                   ushort_t* __restrict__ O,
                                                   int seq0) {
    const int wid = threadIdx.x >> 6;
    const int lane = threadIdx.x & 63;
    const int task = blockIdx.x * 4 + wid;
    const int ns = task / NH;
    const int h = task - ns * NH;
    const int j = (seq0 + ns) & 1;
    const ushort_t* base = QKV + (size_t)(2 * ns) * (3 * DD);
    const int c = h * HDIM + lane;
    const int role1 = (1 + j) * DD;

    const float q0 = b2f(base[c]) + peq[c];
    const float k0 = b2f(base[DD + c]) + pek[c];
    const float v0 = b2f(base[2 * DD + c]);
    const ushort_t* base1 = base + 3 * DD;
    const float q1 = b2f(base1[c]) + peq[role1 + c];
    const float k1 = b2f(base1[DD + c]) + pek[role1 + c];
    const float v1 = b2f(base1[2 * DD + c]);

    float p00 = q0 * k0, p01 = q0 * k1, p10 = q1 * k0, p11 = q1 * k1;
#pragma unroll
    for (int off = 32; off > 0; off >>= 1) {
        p00 += __shfl_xor(p00, off, 64);
        p01 += __shfl_xor(p01, off, 64);
        p10 += __shfl_xor(p10, off, 64);
        p11 += __shfl_xor(p11, off, 64);
    }
    const float sc = 0.125f;
    const float s00 = p00 * sc, s01 = p01 * sc, s10 = p10 * sc, s11 = p11 * sc;

    const float m0 = fmaxf(s00, s01);
    const float e00 = __expf(s00 - m0), e01 = __expf(s01 - m0);
    const float a00 = e00 / (e00 + e01);
    const float o0 = a00 * v0 + (1.0f - a00) * v1;

    const float m1 = fmaxf(s10, s11);
    const float e10 = __expf(s10 - m1), e11 = __expf(s11 - m1);
    const float a10 = e10 / (e10 + e11);
    const float o1 = a10 * v0 + (1.0f - a10) * v1;

    O[(size_t)(2 * ns) * DD + c] = f2b(o0);
    O[(size_t)(2 * ns + 1) * DD + c] = f2b(o1);
}

// ---------------- x_dst = inorm(src), bf16 in/out, one wave per row ----------------
// (residual add is fused into the preceding GEMM epilogue; src already holds x + d)
__global__ __launch_bounds__(256) void inorm_to(const ushort_t* __restrict__ src,
                                                ushort_t* __restrict__ dst) {
    const int wid = threadIdx.x >> 6, lane = threadIdx.x & 63;
    const int r = blockIdx.x * 4 + wid;
    const ushort_t* sr = src + (size_t)r * DD;
    ushort_t* dr = dst + (size_t)r * DD;
    float v[12];
    float s = 0.f, ss = 0.f;
#pragma unroll
    for (int e = 0; e < 3; ++e) {
        const ushort4 xa = ((const ushort4*)sr)[e * 64 + lane];
        const float a0 = b2f(xa.x);
        const float a1 = b2f(xa.y);
        const float a2 = b2f(xa.z);
        const float a3 = b2f(xa.w);
        v[e * 4 + 0] = a0; v[e * 4 + 1] = a1; v[e * 4 + 2] = a2; v[e * 4 + 3] = a3;
        s += a0 + a1 + a2 + a3;
        ss += a0 * a0 + a1 * a1 + a2 * a2 + a3 * a3;
    }
    s = wave_sum64(s); ss = wave_sum64(ss);
    const float mean = s * (1.0f / DD);
    const float var = ss * (1.0f / DD) - mean * mean;
    const float rs = rsqrtf(var + 1e-5f);
#pragma unroll
    for (int e = 0; e < 3; ++e) {
        ushort4 o;
        o.x = f2b((v[e * 4 + 0] - mean) * rs);
        o.y = f2b((v[e * 4 + 1] - mean) * rs);
        o.z = f2b((v[e * 4 + 2] - mean) * rs);
        o.w = f2b((v[e * 4 + 3] - mean) * rs);
        ((ushort4*)dr)[e * 64 + lane] = o;
    }
}

// ---------------- final: out[n] = inorm(x[2n] + x[2n+1]) fp32 out ----------------
__global__ __launch_bounds__(256) void final_inorm(const ushort_t* __restrict__ x,
                                                   float* __restrict__ out) {
    const int wid = threadIdx.x >> 6, lane = threadIdx.x & 63;
    const int n = blockIdx.x * 4 + wid;
    const ushort_t* r0 = x + (size_t)(2 * n) * DD;
    const ushort_t* r1 = r0 + DD;
    float v[12];
    float s = 0.f, ss = 0.f;
#pragma unroll
    for (int e = 0; e < 3; ++e) {
        const ushort4 xa = ((const ushort4*)r0)[e * 64 + lane];
        const ushort4 xb = ((const ushort4*)r1)[e * 64 + lane];
        const float a0 = b2f(xa.x) + b2f(xb.x);
        const float a1 = b2f(xa.y) + b2f(xb.y);
        const float a2 = b2f(xa.z) + b2f(xb.z);
        const float a3 = b2f(xa.w) + b2f(xb.w);
        v[e * 4 + 0] = a0; v[e * 4 + 1] = a1; v[e * 4 + 2] = a2; v[e * 4 + 3] = a3;
        s += a0 + a1 + a2 + a3;
        ss += a0 * a0 + a1 * a1 + a2 * a2 + a3 * a3;
    }
    s = wave_sum64(s); ss = wave_sum64(ss);
    const float mean = s * (1.0f / DD);
    const float var = ss * (1.0f / DD) - mean * mean;
    const float rs = rsqrtf(var + 1e-5f);
    float* orow = out + (size_t)n * DD;
#pragma unroll
    for (int e = 0; e < 3; ++e) {
        float4 o;
        o.x = (v[e * 4 + 0] - mean) * rs;
        o.y = (v[e * 4 + 1] - mean) * rs;
        o.z = (v[e * 4 + 2] - mean) * rs;
        o.w = (v[e * 4 + 3] - mean) * rs;
        ((float4*)orow)[e * 64 + lane] = o;
    }
}

// ---------------- scores ----------------
__global__ __launch_bounds__(256) void score_dot(const ushort_t* __restrict__ pc,
                                                 const ushort_t* __restrict__ cc,
                                                 float* __restrict__ out, int which) {
    const int wid = threadIdx.x >> 6;
    const int lane = threadIdx.x & 63;
    const int row = blockIdx.x * 4 + wid;
    const int b = row >> 5;
    const ushort_t* p = pc + (size_t)b * CSZ;
    const ushort_t* c = cc + (size_t)row * CSZ;
    float s = 0.f;
#pragma unroll
    for (int e = 0; e < 8; ++e) s += b2f(p[e * 64 + lane]) * b2f(c[e * 64 + lane]);
    s = wave_sum64(s);
    if (lane == 0) out[row * 2 + which] = s * 0.04419417382415922f; // 1/sqrt(512)
}

// ---------------- host launch ----------------
extern "C" void kernel_launch(void* const* d_in, const int* in_sizes, int n_in,
                              void* d_out, int out_size, void* d_ws, size_t ws_size,
                              hipStream_t stream) {
    const float* parent = (const float*)d_in[0];
    const float* child  = (const float*)d_in[1];
    const float* aiw = (const float*)d_in[4];
    const float* aib = (const float*)d_in[5];
    const float* aow = (const float*)d_in[6];
    const float* aob = (const float*)d_in[7];
    const float* l1w = (const float*)d_in[8];
    const float* l1b = (const float*)d_in[9];
    const float* l2w = (const float*)d_in[10];
    const float* l2b = (const float*)d_in[11];
    const float* pemb = (const float*)d_in[12];
    const float* pw1 = (const float*)d_in[13];
    const float* pb1 = (const float*)d_in[14];
    const float* pw2 = (const float*)d_in[15];
    const float* pb2 = (const float*)d_in[16];
    const float* lw1 = (const float*)d_in[17];
    const float* lb1 = (const float*)d_in[18];
    const float* lw2 = (const float*)d_in[19];
    const float* lb2 = (const float*)d_in[20];
    const float* rw1 = (const float*)d_in[21];
    const float* rb1 = (const float*)d_in[22];
    const float* rw2 = (const float*)d_in[23];
    const float* rb2 = (const float*)d_in[24];
    float* out = (float*)d_out;
    (void)in_sizes; (void)n_in; (void)out_size;

    // ---- pick chunk rows from workspace ----
    int CH = 8192;
    {
        const size_t fixedB = 100ull * 1024 * 1024;
        if (ws_size >= fixedB + (size_t)32768 * 4608 * 2) CH = 32768;
        else if (ws_size >= fixedB + (size_t)16384 * 4608 * 2) CH = 16384;
    }
    const int NCH = NTOK / CH;

    ushort_t* W0 = (ushort_t*)d_ws;
    size_t off = 0;
    auto take = [&](size_t elems) { ushort_t* p = W0 + off; off += (elems + 127) & ~(size_t)127; return p; };
    ushort_t* aiw_b = take((size_t)LAYERS * 3 * DD * DD);
    ushort_t* aow_b = take((size_t)LAYERS * DD * DD);
    ushort_t* l1w_b = take((size_t)LAYERS * FFD * DD);
    ushort_t* l2w_b = take((size_t)LAYERS * DD * FFD);
    ushort_t* pw1_b = take((size_t)DD * DD);
    ushort_t* pw2_b = take((size_t)CSZ * DD);
    ushort_t* lw1_b = take((size_t)DD * DD);
    ushort_t* lw2_b = take((size_t)CSZ * DD);
    ushort_t* rw1_b = take((size_t)DD * DD);
    ushort_t* rw2_b = take((size_t)CSZ * DD);
    ushort_t* Pb    = take((size_t)NB * DD);
    ushort_t* Xb    = take((size_t)NTOK * DD);
    ushort_t* S1b   = take((size_t)CH * FFD);
    ushort_t* S2b   = take((size_t)CH * DD);
    ushort_t* S3b   = take((size_t)CH * DD);
    ushort_t* P1b   = take((size_t)NB * DD);
    ushort_t* P2b   = take((size_t)NB * CSZ);
    float* PEQ = (float*)(W0 + off); off += 2 * 3 * DD;
    float* PEK = PEQ + 3 * DD;

    auto cvt = [&](const float* s, ushort_t* d, size_t n) {
        cvt_bf16<<<(int)((n + 1023) / 1024), 256, 0, stream>>>(s, d, (int)n);
    };
    // resid only passed for shapes guaranteed to route to gemm_mid (M=CH, N%256==0, K in {768,3072})
    auto gemm = [&](const ushort_t* A, int lda, const ushort_t* Wt, const float* bias,
                    ushort_t* C, int ldc, int M, int N, int K, int dg,
                    const ushort_t* resid = nullptr) {
        if (M % 128 == 0 && N % 256 == 0 && M >= 8192 && K >= 96 && K % 32 == 0) {
            const int MT = M / 128, NT = N / 256;
            const int GM = (MT % 8 == 0) ? 8 : ((MT % 4 == 0) ? 4 : MT);
            int GN = 8;
            while (NT % GN) --GN;
            gemm_mid<<<MT * NT, 512, 0, stream>>>(A, lda, Wt, bias, C, ldc, K, NT, GM, GN, dg, resid);
        } else {
            const int MT = M / 128, NT = N / 128;
            const int GM = (MT % 8 == 0) ? 8 : MT;
            int GN = 8;
            while (NT % GN) --GN;
            gemm_bf16<<<MT * NT, 256, 0, stream>>>(A, lda, Wt, bias, C, ldc, K, NT, GM, GN, dg);
        }
    };

    // ---- weight / input conversions ----
    cvt(aiw, aiw_b, (size_t)LAYERS * 3 * DD * DD);
    cvt(aow, aow_b, (size_t)LAYERS * DD * DD);
    cvt(l1w, l1w_b, (size_t)LAYERS * FFD * DD);
    cvt(l2w, l2w_b, (size_t)LAYERS * DD * FFD);
    cvt_small<<<3072, 256, 0, stream>>>(parent, Pb, pw1, pw1_b, pw2, pw2_b,
                                        lw1, lw1_b, lw2, lw2_b, rw1, rw1_b, rw2, rw2_b);
    cvt(child, S1b, (size_t)NB * NC * 2 * DD);   // child bf16 into S1b [16384][768]

    // ---- build x0 ----
    build_x<<<NTOK, 192, 0, stream>>>(parent, child, Xb);

    // ---- outside scores ----
    gemm(Pb, DD, pw1_b, pb1, P1b, DD, NB, DD, DD, 1);
    gemm(P1b, DD, pw2_b, pb2, P2b, CSZ, NB, CSZ, DD, 0);
    gemm(S1b, 2 * DD, lw1_b, lb1, S2b, DD, NB * NC, DD, DD, 1);
    gemm(S2b, DD, lw2_b, lb2, S3b, CSZ, NB * NC, CSZ, DD, 0);
    score_dot<<<NB * NC / 4, 256, 0, stream>>>(P2b, S3b, out, 1);
    gemm(S1b + DD, 2 * DD, rw1_b, rb1, S2b, DD, NB * NC, DD, DD, 1);
    gemm(S2b, DD, rw2_b, rb2, S3b, CSZ, NB * NC, CSZ, DD, 0);
    score_dot<<<NB * NC / 4, 256, 0, stream>>>(P2b, S3b, out, 0);

    // ---- transformer layers ----
    for (int l = 0; l < LAYERS; ++l) {
        const ushort_t* Wl  = aiw_b + (size_t)l * 3 * DD * DD;
        const float* bl  = aib + (size_t)l * 3 * DD;
        const ushort_t* owl = aow_b + (size_t)l * DD * DD;
        const float* obl = aob + (size_t)l * DD;
        const ushort_t* w1l = l1w_b + (size_t)l * FFD * DD;
        const float* b1l = l1b + (size_t)l * FFD;
        const ushort_t* w2l = l2w_b + (size_t)l * DD * FFD;
        const float* b2l = l2b + (size_t)l * DD;

        pe_proj<<<2 * 3 * DD / 4, 256, 0, stream>>>(pemb + (size_t)l * 4 * DD,
                                                    aiw + (size_t)l * 3 * DD * DD, PEQ, PEK);

        for (int c = 0; c < NCH; ++c) {
            ushort_t* Xc = Xb + (size_t)c * CH * DD;
            gemm(Xc, DD, Wl, bl, S1b, 3 * DD, CH, 3 * DD, DD, 0);
            attn_kernel<<<(CH / 2) * NH / 4, 256, 0, stream>>>(S1b, PEQ, PEK, S2b, c * (CH / 2));
            gemm(S2b, DD, owl, obl, S3b, DD, CH, DD, DD, 0, Xc);   // S3 = attn@W_o + b + x
            inorm_to<<<CH / 4, 256, 0, stream>>>(S3b, Xc);          // x = inorm(S3)
            gemm(Xc, DD, w1l, b1l, S1b, FFD, CH, FFD, DD, 1);
            gemm(S1b, FFD, w2l, b2l, S3b, DD, CH, DD, FFD, 0, Xc); // S3 = ff@W2 + b + x
            inorm_to<<<CH / 4, 256, 0, stream>>>(S3b, Xc);          // x = inorm(S3)
        }
    }

    // ---- final: inorm over token-sum ----
    final_inorm<<<NSEQ / 4, 256, 0, stream>>>(Xb, out + NSEQ);
}